// Round 8
// baseline (65523.846 us; speedup 1.0000x reference)
//
#include <hip/hip_runtime.h>
#include <hip/hip_bf16.h>

#define B_ 4
#define S_ 2048
#define D_ 768
#define H_ 12
#define HD_ 64
#define M_ (B_*S_)   // 8192

typedef unsigned short u16;
typedef unsigned int   u32;

__device__ __forceinline__ float bf2f(u16 u) {
  union { u32 i; float f; } c; c.i = ((u32)u) << 16; return c.f;
}
__device__ __forceinline__ u16 f2bf(float x) {
  union { float f; u32 i; } c; c.f = x;
  u32 r = (c.i + 0x7FFFu + ((c.i >> 16) & 1u)) >> 16;
  return (u16)r;
}

// Per-buffer dtype probe (guard; inputs proven f32). f32 low halves trip the
// bf16-exponent>=0x88 test w.p. ~1-4e-18 over 64 samples; bf16 N(0,1) never.
__device__ __forceinline__ int buf_is_f32(const void* p) {
  const uint4* q = (const uint4*)p;
  int bad = 0;
#pragma unroll
  for (int i = 0; i < 16; ++i) {
    uint4 v = q[i];
    u32 a[4] = {v.x, v.y, v.z, v.w};
#pragma unroll
    for (int j = 0; j < 4; ++j) {
      bad |= (int)(((a[j] >> 7)  & 0xFFu) >= 0x88u);
      bad |= (int)(((a[j] >> 23) & 0xFFu) >= 0x88u);
    }
  }
  return bad;
}

__device__ __forceinline__ float rd(const void* p, int isf, size_t idx) {
  return isf ? ((const float*)p)[idx] : bf2f(((const u16*)p)[idx]);
}

// Naive GEMM: C[m][n] = sum_k A[m][k] * W[n][k]; A,W dtype auto-probed; C bf16.
__global__ __launch_bounds__(256) void gemm_naive_auto(const void* __restrict__ A,
                                                       const void* __restrict__ W,
                                                       u16* __restrict__ C)
{
  const int af = buf_is_f32(A);
  const int wf = buf_is_f32(W);
  int m = blockIdx.x;
  int n = blockIdx.y * 256 + threadIdx.x;
  size_t ao = (size_t)m * D_;
  size_t wo = (size_t)n * D_;
  float acc = 0.f;
  for (int k = 0; k < D_; ++k) acc += rd(A, af, ao + k) * rd(W, wf, wo + k);
  C[(size_t)m * D_ + n] = f2bf(acc);
}

// Final GEMM: A bf16 (attention output), W auto-probed, C *** f32 *** -> d_out.
__global__ __launch_bounds__(256) void gemm_out_f32(const u16* __restrict__ A,
                                                    const void* __restrict__ W,
                                                    float* __restrict__ C)
{
  const int wf = buf_is_f32(W);
  int m = blockIdx.x;
  int n = blockIdx.y * 256 + threadIdx.x;
  const u16* a = A + (size_t)m * D_;
  size_t wo = (size_t)n * D_;
  float acc = 0.f;
  for (int k = 0; k < D_; ++k) acc += bf2f(a[k]) * rd(W, wf, wo + k);
  C[(size_t)m * D_ + n] = acc;
}

// Naive per-head L2 normalize (in place), one THREAD per (row, head) vector.
__global__ __launch_bounds__(256) void norm_naive(u16* __restrict__ P,
                                                  const void* __restrict__ temp,
                                                  int use_temp)
{
  int vec = blockIdx.x * 256 + threadIdx.x;   // 0 .. M*H-1
  if (vec >= M_ * H_) return;
  int row = vec / H_;
  int h   = vec % H_;
  u16* p = P + (size_t)row * D_ + h * HD_;
  float s = 0.f;
  for (int d = 0; d < HD_; ++d) { float v = bf2f(p[d]); s += v * v; }
  float scl = 1.0f / fmaxf(sqrtf(s), 1e-12f);
  if (use_temp) {
    u32 w0 = *(const u32*)temp;  // f32 1.0 has zero low half; bf16 1.0 = 0x3F80
    float t = ((w0 & 0xFFFFu) == 0u) ? ((const float*)temp)[h]
                                     : bf2f(((const u16*)temp)[h]);
    scl *= t;
  }
  for (int d = 0; d < HD_; ++d) p[d] = f2bf(bf2f(p[d]) * scl);
}

// Naive causal attention: one WAVE per (bh, q-row). lane = d (0..63).
// Online softmax; O overwrites Q (each wave reads only its own Q row, first).
__global__ __launch_bounds__(256) void attn_naive(const u16* __restrict__ Q,
                                                  const u16* __restrict__ K,
                                                  const u16* __restrict__ V,
                                                  u16* __restrict__ O)
{
  int w    = threadIdx.x >> 6;
  int lane = threadIdx.x & 63;
  int wid  = blockIdx.x * 4 + w;        // 0 .. 48*2048-1
  int bh   = wid >> 11;
  int s    = wid & 2047;
  int b = bh / H_, h = bh % H_;
  const size_t base = (size_t)b * S_ * D_ + (size_t)h * HD_;

  float q = bf2f(Q[base + (size_t)s * D_ + lane]);

  float m = -__builtin_inff(), l = 0.f, acc = 0.f;
  for (int t = 0; t <= s; ++t) {
    float prod = q * bf2f(K[base + (size_t)t * D_ + lane]);
#pragma unroll
    for (int msk = 1; msk < 64; msk <<= 1) prod += __shfl_xor(prod, msk, 64);
    float score = prod;                  // temperature folded into Q
    float mn   = fmaxf(m, score);
    float corr = expf(m - mn);
    float p    = expf(score - mn);
    l   = l * corr + p;
    acc = acc * corr + p * bf2f(V[base + (size_t)t * D_ + lane]);
    m = mn;
  }
  O[base + (size_t)s * D_ + lane] = f2bf(acc / l);
}

extern "C" void kernel_launch(void* const* d_in, const int* in_sizes, int n_in,
                              void* d_out, int out_size, void* d_ws, size_t ws_size,
                              hipStream_t stream) {
  // Input remap guard: x is the only 6291456-elem input.
  const void *x, *Wq, *Wk, *Wv, *Wo, *temp;
  if (in_sizes[0] == M_ * D_) {
    x = d_in[0]; Wq = d_in[1]; Wk = d_in[2]; Wv = d_in[3]; Wo = d_in[4]; temp = d_in[5];
  } else {
    Wk = d_in[0]; Wo = d_in[1]; Wq = d_in[2]; Wv = d_in[3]; temp = d_in[4]; x = d_in[5];
  }

  const size_t SZ = (size_t)M_ * D_;   // 6291456 elems
  u16* ws = (u16*)d_ws;
  u16* Qb = ws;            // ws usage: 3*SZ*2 = 37,748,736 bytes
  u16* Kb = ws + SZ;
  u16* Vb = ws + 2 * SZ;

  dim3 gg(M_, D_ / 256), bb(256);
  gemm_naive_auto<<<gg, bb, 0, stream>>>(x, Wq, Qb);
  gemm_naive_auto<<<gg, bb, 0, stream>>>(x, Wk, Kb);
  gemm_naive_auto<<<gg, bb, 0, stream>>>(x, Wv, Vb);

  int nvec = M_ * H_;
  norm_naive<<<(nvec + 255) / 256, 256, 0, stream>>>(Qb, temp, 1);
  norm_naive<<<(nvec + 255) / 256, 256, 0, stream>>>(Kb, temp, 0);

  attn_naive<<<(B_ * H_ * S_) / 4, 256, 0, stream>>>(Qb, Kb, Vb, Qb);

  // *** output written as f32 ***
  gemm_out_f32<<<gg, bb, 0, stream>>>(Qb, Wo, (float*)d_out);
}

// Round 9
// 648.325 us; speedup vs baseline: 101.0663x; 101.0663x over previous
//
#include <hip/hip_runtime.h>
#include <hip/hip_bf16.h>

#define B_ 4
#define S_ 2048
#define D_ 768
#define H_ 12
#define HD_ 64
#define M_ (B_*S_)   // 8192

typedef __attribute__((ext_vector_type(8))) short bf8;
typedef __attribute__((ext_vector_type(4))) float f4;
typedef unsigned short u16;
typedef unsigned int   u32;

__device__ __forceinline__ float bf2f(u16 u) {
  union { u32 i; float f; } c; c.i = ((u32)u) << 16; return c.f;
}
__device__ __forceinline__ u16 f2bf(float x) {
  union { float f; u32 i; } c; c.f = x;
  u32 r = (c.i + 0x7FFFu + ((c.i >> 16) & 1u)) >> 16;
  return (u16)r;
}

// f32 -> bf16 (rne), vectorized x4, grid-stride.
__global__ __launch_bounds__(256) void stage_x(const float* __restrict__ in,
                                               u16* __restrict__ out, int n4)
{
  for (int i = blockIdx.x * blockDim.x + threadIdx.x; i < n4; i += gridDim.x * blockDim.x) {
    float4 v = ((const float4*)in)[i];
    ushort4 o;
    o.x = f2bf(v.x); o.y = f2bf(v.y); o.z = f2bf(v.z); o.w = f2bf(v.w);
    ((ushort4*)out)[i] = o;
  }
}

// Load 8 consecutive f32 and convert to a bf16x8 fragment.
__device__ __forceinline__ bf8 ldcvt8(const float* __restrict__ p) {
  float4 a = *(const float4*)p;
  float4 b = *(const float4*)(p + 4);
  bf8 r;
  r[0] = f2bf(a.x); r[1] = f2bf(a.y); r[2] = f2bf(a.z); r[3] = f2bf(a.w);
  r[4] = f2bf(b.x); r[5] = f2bf(b.y); r[6] = f2bf(b.z); r[7] = f2bf(b.w);
  return r;
}

// C[m][n] = sum_k A[m][k] * W[n][k]; A bf16 [M,K], W f32 [N,K] (inline cvt).
// OUT_F32: store f32 to Cf, else bf16 to Cb.
// Block: 256 thr = 4 waves (2x2), tile 64x128, wave 32x64.
template <int OUT_F32>
__global__ __launch_bounds__(256) void gemm_bt_wf32(const u16* __restrict__ A,
                                                    const float* __restrict__ W,
                                                    u16* __restrict__ Cb,
                                                    float* __restrict__ Cf,
                                                    int M, int N, int K)
{
  const int w  = threadIdx.x >> 6;
  const int ln = threadIdx.x & 63;
  const int li = ln & 15, g = ln >> 4;
  const int wr = w >> 1, wc = w & 1;
  const int row0 = blockIdx.x * 64 + wr * 32;
  const int col0 = blockIdx.y * 128 + wc * 64;

  const u16*   Ap = A + (size_t)(row0 + li) * K + g * 8;
  const float* Wp = W + (size_t)(col0 + li) * K + g * 8;

  f4 acc[2][4];
#pragma unroll
  for (int i = 0; i < 2; ++i)
#pragma unroll
    for (int j = 0; j < 4; ++j) acc[i][j] = (f4){0.f, 0.f, 0.f, 0.f};

  for (int k = 0; k < K; k += 32) {
    bf8 a0 = *(const bf8*)(Ap + k);
    bf8 a1 = *(const bf8*)(Ap + (size_t)16 * K + k);
    bf8 b0 = ldcvt8(Wp + k);
    bf8 b1 = ldcvt8(Wp + (size_t)16 * K + k);
    bf8 b2 = ldcvt8(Wp + (size_t)32 * K + k);
    bf8 b3 = ldcvt8(Wp + (size_t)48 * K + k);
    acc[0][0] = __builtin_amdgcn_mfma_f32_16x16x32_bf16(a0, b0, acc[0][0], 0, 0, 0);
    acc[0][1] = __builtin_amdgcn_mfma_f32_16x16x32_bf16(a0, b1, acc[0][1], 0, 0, 0);
    acc[0][2] = __builtin_amdgcn_mfma_f32_16x16x32_bf16(a0, b2, acc[0][2], 0, 0, 0);
    acc[0][3] = __builtin_amdgcn_mfma_f32_16x16x32_bf16(a0, b3, acc[0][3], 0, 0, 0);
    acc[1][0] = __builtin_amdgcn_mfma_f32_16x16x32_bf16(a1, b0, acc[1][0], 0, 0, 0);
    acc[1][1] = __builtin_amdgcn_mfma_f32_16x16x32_bf16(a1, b1, acc[1][1], 0, 0, 0);
    acc[1][2] = __builtin_amdgcn_mfma_f32_16x16x32_bf16(a1, b2, acc[1][2], 0, 0, 0);
    acc[1][3] = __builtin_amdgcn_mfma_f32_16x16x32_bf16(a1, b3, acc[1][3], 0, 0, 0);
  }

#pragma unroll
  for (int i = 0; i < 2; ++i)
#pragma unroll
    for (int j = 0; j < 4; ++j)
#pragma unroll
      for (int r = 0; r < 4; ++r) {
        int row = row0 + i * 16 + g * 4 + r;
        int col = col0 + j * 16 + li;
        if (OUT_F32) Cf[(size_t)row * N + col] = acc[i][j][r];
        else         Cb[(size_t)row * N + col] = f2bf(acc[i][j][r]);
      }
}

// L2-normalize each 64-elem head vector in place; optionally fold temperature[h] (f32).
__global__ __launch_bounds__(256) void norm_heads(u16* __restrict__ P,
                                                  const float* __restrict__ temp,
                                                  int use_temp)
{
  int vec  = blockIdx.x * 4 + (threadIdx.x >> 6);
  int lane = threadIdx.x & 63;
  int row  = vec / H_;
  int h    = vec % H_;
  u16* p = P + (size_t)row * D_ + h * HD_ + lane;
  float v = bf2f(*p);
  float s = v * v;
#pragma unroll
  for (int m = 1; m < 64; m <<= 1) s += __shfl_xor(s, m, 64);
  float nrm = fmaxf(sqrtf(s), 1e-12f);
  float scl = 1.0f / nrm;
  if (use_temp) scl *= temp[h];
  *p = f2bf(v * scl);
}

// Flash attention, causal, temperature pre-folded into Q.
// Grid: (32 q-tiles, 48 bh). Block: 256 thr = 4 waves; wave owns 16 q-rows.
// O may alias Q (each block writes only the Q rows it alone reads, read-first).
__global__ __launch_bounds__(256) void flash_attn(const u16* __restrict__ Q,
                                                  const u16* __restrict__ K,
                                                  const u16* __restrict__ V,
                                                  u16* __restrict__ O)
{
  const int qt = blockIdx.x;
  const int bh = blockIdx.y;
  const int b = bh / H_, h = bh % H_;
  const size_t base = (size_t)b * S_ * D_ + h * HD_;
  const u16* Qp = Q + base;
  const u16* Kp = K + base;
  const u16* Vp = V + base;
  u16*       Op = O + base;

  const int w  = threadIdx.x >> 6;
  const int ln = threadIdx.x & 63;
  const int li = ln & 15, g = ln >> 4;

  __shared__ __align__(16) u16 v_lds[64][80];      // row stride 160B
  __shared__ __align__(16) u16 p_lds[4][16][72];   // row stride 144B

  const int q0 = qt * 64;
  const int qrow = q0 + w * 16 + li;

  bf8 qf0 = *(const bf8*)(Qp + (size_t)qrow * D_ + g * 8);
  bf8 qf1 = *(const bf8*)(Qp + (size_t)qrow * D_ + 32 + g * 8);

  f4 o[4];
  float m[4], l[4];
#pragma unroll
  for (int r = 0; r < 4; ++r) { m[r] = -__builtin_inff(); l[r] = 0.f; }
#pragma unroll
  for (int c = 0; c < 4; ++c) o[c] = (f4){0.f, 0.f, 0.f, 0.f};

  for (int kt = 0; kt <= qt; ++kt) {
    __syncthreads();
    {
      int t = threadIdx.x;
      int vc = (t & 7) * 8;
      int vr = t >> 3;  // 0..31
      *(bf8*)&v_lds[vr][vc]      = *(const bf8*)(Vp + (size_t)(kt * 64 + vr) * D_ + vc);
      *(bf8*)&v_lds[vr + 32][vc] = *(const bf8*)(Vp + (size_t)(kt * 64 + vr + 32) * D_ + vc);
    }
    __syncthreads();

    f4 sc[4];
#pragma unroll
    for (int c = 0; c < 4; ++c) sc[c] = (f4){0.f, 0.f, 0.f, 0.f};
#pragma unroll
    for (int c = 0; c < 4; ++c) {
      const u16* kb = Kp + (size_t)(kt * 64 + c * 16 + li) * D_ + g * 8;
      bf8 k0 = *(const bf8*)(kb);
      bf8 k1 = *(const bf8*)(kb + 32);
      sc[c] = __builtin_amdgcn_mfma_f32_16x16x32_bf16(qf0, k0, sc[c], 0, 0, 0);
      sc[c] = __builtin_amdgcn_mfma_f32_16x16x32_bf16(qf1, k1, sc[c], 0, 0, 0);
    }

    if (kt == qt) {
#pragma unroll
      for (int c = 0; c < 4; ++c)
#pragma unroll
        for (int r = 0; r < 4; ++r) {
          int col = kt * 64 + c * 16 + li;
          int row = q0 + w * 16 + g * 4 + r;
          if (col > row) sc[c][r] = -__builtin_inff();
        }
    }

    float pm[4], scale[4];
#pragma unroll
    for (int r = 0; r < 4; ++r) {
      float x = fmaxf(fmaxf(sc[0][r], sc[1][r]), fmaxf(sc[2][r], sc[3][r]));
#pragma unroll
      for (int msk = 1; msk < 16; msk <<= 1) x = fmaxf(x, __shfl_xor(x, msk, 64));
      pm[r] = x;
    }
#pragma unroll
    for (int r = 0; r < 4; ++r) {
      float mn = fmaxf(m[r], pm[r]);
      scale[r] = expf(m[r] - mn);
      m[r] = mn;
    }
    float ps[4] = {0.f, 0.f, 0.f, 0.f};
#pragma unroll
    for (int c = 0; c < 4; ++c)
#pragma unroll
      for (int r = 0; r < 4; ++r) {
        float p = expf(sc[c][r] - m[r]);
        sc[c][r] = p;
        ps[r] += p;
      }
#pragma unroll
    for (int r = 0; r < 4; ++r) {
#pragma unroll
      for (int msk = 1; msk < 16; msk <<= 1) ps[r] += __shfl_xor(ps[r], msk, 64);
      l[r] = l[r] * scale[r] + ps[r];
    }
#pragma unroll
    for (int c = 0; c < 4; ++c)
#pragma unroll
      for (int r = 0; r < 4; ++r) o[c][r] *= scale[r];

#pragma unroll
    for (int c = 0; c < 4; ++c)
#pragma unroll
      for (int r = 0; r < 4; ++r)
        p_lds[w][g * 4 + r][c * 16 + li] = f2bf(sc[c][r]);

#pragma unroll
    for (int ks = 0; ks < 2; ++ks) {
      bf8 pa = *(const bf8*)&p_lds[w][li][ks * 32 + g * 8];
#pragma unroll
      for (int c = 0; c < 4; ++c) {
        bf8 vb;
#pragma unroll
        for (int j = 0; j < 8; ++j)
          vb[j] = (short)v_lds[ks * 32 + g * 8 + j][c * 16 + li];
        o[c] = __builtin_amdgcn_mfma_f32_16x16x32_bf16(pa, vb, o[c], 0, 0, 0);
      }
    }
  }

#pragma unroll
  for (int c = 0; c < 4; ++c)
#pragma unroll
    for (int r = 0; r < 4; ++r) {
      int row = q0 + w * 16 + g * 4 + r;
      Op[(size_t)row * D_ + c * 16 + li] = f2bf(o[c][r] / l[r]);
    }
}

extern "C" void kernel_launch(void* const* d_in, const int* in_sizes, int n_in,
                              void* d_out, int out_size, void* d_ws, size_t ws_size,
                              hipStream_t stream) {
  // Input remap guard: x is the only 6291456-elem input.
  const void *xv, *Wqv, *Wkv, *Wvv, *Wov, *tv;
  if (in_sizes[0] == M_ * D_) {
    xv = d_in[0]; Wqv = d_in[1]; Wkv = d_in[2]; Wvv = d_in[3]; Wov = d_in[4]; tv = d_in[5];
  } else {
    Wkv = d_in[0]; Wov = d_in[1]; Wqv = d_in[2]; Wvv = d_in[3]; tv = d_in[4]; xv = d_in[5];
  }
  const float* x    = (const float*)xv;
  const float* Wq   = (const float*)Wqv;
  const float* Wk   = (const float*)Wkv;
  const float* Wv   = (const float*)Wvv;
  const float* Wo   = (const float*)Wov;
  const float* temp = (const float*)tv;

  const size_t SZ = (size_t)M_ * D_;   // 6291456 elems
  u16* ws = (u16*)d_ws;
  u16* Qb = ws;            // ws usage: 3*SZ*2 = 37,748,736 bytes (proven region)
  u16* Kb = ws + SZ;
  u16* Vb = ws + 2 * SZ;
  u16* XB = (u16*)d_out;   // bf16(x) staged in d_out (scratch until final GEMM)

  stage_x<<<2048, 256, 0, stream>>>(x, XB, (int)(SZ / 4));

  dim3 gg(M_ / 64, D_ / 128), bb(256);
  gemm_bt_wf32<0><<<gg, bb, 0, stream>>>(XB, Wq, Qb, nullptr, M_, D_, D_);
  gemm_bt_wf32<0><<<gg, bb, 0, stream>>>(XB, Wk, Kb, nullptr, M_, D_, D_);
  gemm_bt_wf32<0><<<gg, bb, 0, stream>>>(XB, Wv, Vb, nullptr, M_, D_, D_);

  norm_heads<<<(M_ * H_) / 4, 256, 0, stream>>>(Qb, temp, 1);
  norm_heads<<<(M_ * H_) / 4, 256, 0, stream>>>(Kb, temp, 0);

  // attention output overwrites Qb (safe: per-block exclusive rows/cols)
  flash_attn<<<dim3(S_ / 64, B_ * H_), 256, 0, stream>>>(Qb, Kb, Vb, Qb);

  // final GEMM: f32 output
  gemm_bt_wf32<1><<<gg, bb, 0, stream>>>(Qb, Wo, nullptr, (float*)d_out, M_, D_, D_);
}

// Round 10
// 450.228 us; speedup vs baseline: 145.5349x; 1.4400x over previous
//
#include <hip/hip_runtime.h>
#include <hip/hip_bf16.h>

#define B_ 4
#define S_ 2048
#define D_ 768
#define H_ 12
#define HD_ 64
#define M_ (B_*S_)   // 8192

typedef __attribute__((ext_vector_type(8))) short bf8;
typedef __attribute__((ext_vector_type(4))) float f4;
typedef unsigned short u16;
typedef unsigned int   u32;

__device__ __forceinline__ float bf2f(u16 u) {
  union { u32 i; float f; } c; c.i = ((u32)u) << 16; return c.f;
}
__device__ __forceinline__ u16 f2bf(float x) {
  union { float f; u32 i; } c; c.f = x;
  u32 r = (c.i + 0x7FFFu + ((c.i >> 16) & 1u)) >> 16;
  return (u16)r;
}

// f32 -> bf16 (rne), vectorized x4, grid-stride.
__global__ __launch_bounds__(256) void stage_cvt(const float* __restrict__ in,
                                                 u16* __restrict__ out, int n4)
{
  for (int i = blockIdx.x * blockDim.x + threadIdx.x; i < n4; i += gridDim.x * blockDim.x) {
    float4 v = ((const float4*)in)[i];
    ushort4 o;
    o.x = f2bf(v.x); o.y = f2bf(v.y); o.z = f2bf(v.z); o.w = f2bf(v.w);
    ((ushort4*)out)[i] = o;
  }
}

__device__ __forceinline__ bf8 ldcvt8(const float* __restrict__ p) {
  float4 a = *(const float4*)p;
  float4 b = *(const float4*)(p + 4);
  bf8 r;
  r[0] = f2bf(a.x); r[1] = f2bf(a.y); r[2] = f2bf(a.z); r[3] = f2bf(a.w);
  r[4] = f2bf(b.x); r[5] = f2bf(b.y); r[6] = f2bf(b.z); r[7] = f2bf(b.w);
  return r;
}

// C[m][n] = sum_k A[m][k] * W[n][k]; A bf16 [M,K]; W bf16 (WBF16=1) or f32.
// EPI: 0 = bf16 store; 1 = head-L2-normalize then bf16; 2 = normalize*temp[h];
//      3 = f32 store (final output GEMM).
// Block: 256 thr = 4 waves (2x2), tile 64x128, wave 32x64 (= 1 head x 32 rows).
template <int WBF16, int EPI>
__global__ __launch_bounds__(256) void gemm_fused(const u16* __restrict__ A,
                                                  const void* __restrict__ Wv,
                                                  u16* __restrict__ Cb,
                                                  float* __restrict__ Cf,
                                                  const float* __restrict__ temp,
                                                  int M, int N, int K)
{
  const int w  = threadIdx.x >> 6;
  const int ln = threadIdx.x & 63;
  const int li = ln & 15, g = ln >> 4;
  const int wr = w >> 1, wc = w & 1;
  const int row0 = blockIdx.x * 64 + wr * 32;
  const int col0 = blockIdx.y * 128 + wc * 64;

  const u16* Ap = A + (size_t)(row0 + li) * K + g * 8;

  f4 acc[2][4];
#pragma unroll
  for (int i = 0; i < 2; ++i)
#pragma unroll
    for (int j = 0; j < 4; ++j) acc[i][j] = (f4){0.f, 0.f, 0.f, 0.f};

  if (WBF16) {
    const u16* Wp = (const u16*)Wv + (size_t)(col0 + li) * K + g * 8;
    for (int k = 0; k < K; k += 32) {
      bf8 a0 = *(const bf8*)(Ap + k);
      bf8 a1 = *(const bf8*)(Ap + (size_t)16 * K + k);
      bf8 b0 = *(const bf8*)(Wp + k);
      bf8 b1 = *(const bf8*)(Wp + (size_t)16 * K + k);
      bf8 b2 = *(const bf8*)(Wp + (size_t)32 * K + k);
      bf8 b3 = *(const bf8*)(Wp + (size_t)48 * K + k);
      acc[0][0] = __builtin_amdgcn_mfma_f32_16x16x32_bf16(a0, b0, acc[0][0], 0, 0, 0);
      acc[0][1] = __builtin_amdgcn_mfma_f32_16x16x32_bf16(a0, b1, acc[0][1], 0, 0, 0);
      acc[0][2] = __builtin_amdgcn_mfma_f32_16x16x32_bf16(a0, b2, acc[0][2], 0, 0, 0);
      acc[0][3] = __builtin_amdgcn_mfma_f32_16x16x32_bf16(a0, b3, acc[0][3], 0, 0, 0);
      acc[1][0] = __builtin_amdgcn_mfma_f32_16x16x32_bf16(a1, b0, acc[1][0], 0, 0, 0);
      acc[1][1] = __builtin_amdgcn_mfma_f32_16x16x32_bf16(a1, b1, acc[1][1], 0, 0, 0);
      acc[1][2] = __builtin_amdgcn_mfma_f32_16x16x32_bf16(a1, b2, acc[1][2], 0, 0, 0);
      acc[1][3] = __builtin_amdgcn_mfma_f32_16x16x32_bf16(a1, b3, acc[1][3], 0, 0, 0);
    }
  } else {
    const float* Wp = (const float*)Wv + (size_t)(col0 + li) * K + g * 8;
    for (int k = 0; k < K; k += 32) {
      bf8 a0 = *(const bf8*)(Ap + k);
      bf8 a1 = *(const bf8*)(Ap + (size_t)16 * K + k);
      bf8 b0 = ldcvt8(Wp + k);
      bf8 b1 = ldcvt8(Wp + (size_t)16 * K + k);
      bf8 b2 = ldcvt8(Wp + (size_t)32 * K + k);
      bf8 b3 = ldcvt8(Wp + (size_t)48 * K + k);
      acc[0][0] = __builtin_amdgcn_mfma_f32_16x16x32_bf16(a0, b0, acc[0][0], 0, 0, 0);
      acc[0][1] = __builtin_amdgcn_mfma_f32_16x16x32_bf16(a0, b1, acc[0][1], 0, 0, 0);
      acc[0][2] = __builtin_amdgcn_mfma_f32_16x16x32_bf16(a0, b2, acc[0][2], 0, 0, 0);
      acc[0][3] = __builtin_amdgcn_mfma_f32_16x16x32_bf16(a0, b3, acc[0][3], 0, 0, 0);
      acc[1][0] = __builtin_amdgcn_mfma_f32_16x16x32_bf16(a1, b0, acc[1][0], 0, 0, 0);
      acc[1][1] = __builtin_amdgcn_mfma_f32_16x16x32_bf16(a1, b1, acc[1][1], 0, 0, 0);
      acc[1][2] = __builtin_amdgcn_mfma_f32_16x16x32_bf16(a1, b2, acc[1][2], 0, 0, 0);
      acc[1][3] = __builtin_amdgcn_mfma_f32_16x16x32_bf16(a1, b3, acc[1][3], 0, 0, 0);
    }
  }

  if (EPI == 1 || EPI == 2) {
    // wave sub-tile = rows [row0+..32) x one full head (cols col0..col0+63).
    float tmul = 1.0f;
    if (EPI == 2) tmul = temp[(col0 >> 6)];   // head h = col0/64
#pragma unroll
    for (int i = 0; i < 2; ++i)
#pragma unroll
      for (int r = 0; r < 4; ++r) {
        float ss = 0.f;
#pragma unroll
        for (int j = 0; j < 4; ++j) ss += acc[i][j][r] * acc[i][j][r];
#pragma unroll
        for (int msk = 1; msk < 16; msk <<= 1) ss += __shfl_xor(ss, msk, 64);
        float scl = tmul / fmaxf(sqrtf(ss), 1e-12f);
#pragma unroll
        for (int j = 0; j < 4; ++j) acc[i][j][r] *= scl;
      }
  }

#pragma unroll
  for (int i = 0; i < 2; ++i)
#pragma unroll
    for (int j = 0; j < 4; ++j)
#pragma unroll
      for (int r = 0; r < 4; ++r) {
        int row = row0 + i * 16 + g * 4 + r;
        int col = col0 + j * 16 + li;
        if (EPI == 3) Cf[(size_t)row * N + col] = acc[i][j][r];
        else          Cb[(size_t)row * N + col] = f2bf(acc[i][j][r]);
      }
}

// Flash attention, causal, temperature pre-folded into Q.
// Grid: (32 q-tiles reversed, 48 bh). Block: 256 thr = 4 waves; wave owns 16 q-rows.
// V staged TRANSPOSED in LDS (vt[d][key^swz]) so PV B-fragments are ds_read_b128.
// O may alias Q (per-block exclusive rows, read-first).
__global__ __launch_bounds__(256) void flash_attn(const u16* __restrict__ Q,
                                                  const u16* __restrict__ K,
                                                  const u16* __restrict__ V,
                                                  u16* __restrict__ O)
{
  const int qt = (gridDim.x - 1) - blockIdx.x;   // heavy tiles dispatch first
  const int bh = blockIdx.y;
  const int b = bh / H_, h = bh % H_;
  const size_t base = (size_t)b * S_ * D_ + h * HD_;
  const u16* Qp = Q + base;
  const u16* Kp = K + base;
  const u16* Vp = V + base;
  u16*       Op = O + base;

  const int w  = threadIdx.x >> 6;
  const int ln = threadIdx.x & 63;
  const int li = ln & 15, g = ln >> 4;

  __shared__ __align__(16) u16 vt[64][72];         // [d][key^swz], stride 144B
  __shared__ __align__(16) u16 p_lds[4][16][72];   // per-wave P, stride 144B

  const int q0 = qt * 64;
  const int qrow = q0 + w * 16 + li;

  bf8 qf0 = *(const bf8*)(Qp + (size_t)qrow * D_ + g * 8);
  bf8 qf1 = *(const bf8*)(Qp + (size_t)qrow * D_ + 32 + g * 8);

  f4 o[4];
  float m[4], l[4];
#pragma unroll
  for (int r = 0; r < 4; ++r) { m[r] = -__builtin_inff(); l[r] = 0.f; }
#pragma unroll
  for (int c = 0; c < 4; ++c) o[c] = (f4){0.f, 0.f, 0.f, 0.f};

  for (int kt = 0; kt <= qt; ++kt) {
    __syncthreads();
    {
      // stage V transposed: thread t loads V[key=vr][d=vc..vc+7] (2 key rows),
      // writes vt[d][key ^ vc] (swizzle spreads banks; bijective per d-row).
      int t  = threadIdx.x;
      int vc = (t & 7) * 8;           // d-offset; (vc>>3)<<3 == vc
      int vr = t >> 3;                // key 0..31
      bf8 v0 = *(const bf8*)(Vp + (size_t)(kt * 64 + vr) * D_ + vc);
      bf8 v1 = *(const bf8*)(Vp + (size_t)(kt * 64 + vr + 32) * D_ + vc);
#pragma unroll
      for (int j = 0; j < 8; ++j) {
        vt[vc + j][vr ^ vc]        = (u16)v0[j];
        vt[vc + j][(vr + 32) ^ vc] = (u16)v1[j];
      }
    }
    __syncthreads();

    f4 sc[4];
#pragma unroll
    for (int c = 0; c < 4; ++c) sc[c] = (f4){0.f, 0.f, 0.f, 0.f};
#pragma unroll
    for (int c = 0; c < 4; ++c) {
      const u16* kb = Kp + (size_t)(kt * 64 + c * 16 + li) * D_ + g * 8;
      bf8 k0 = *(const bf8*)(kb);
      bf8 k1 = *(const bf8*)(kb + 32);
      sc[c] = __builtin_amdgcn_mfma_f32_16x16x32_bf16(qf0, k0, sc[c], 0, 0, 0);
      sc[c] = __builtin_amdgcn_mfma_f32_16x16x32_bf16(qf1, k1, sc[c], 0, 0, 0);
    }

    if (kt == qt) {
#pragma unroll
      for (int c = 0; c < 4; ++c)
#pragma unroll
        for (int r = 0; r < 4; ++r) {
          int col = kt * 64 + c * 16 + li;
          int row = q0 + w * 16 + g * 4 + r;
          if (col > row) sc[c][r] = -__builtin_inff();
        }
    }

    float pm[4], scale[4];
#pragma unroll
    for (int r = 0; r < 4; ++r) {
      float x = fmaxf(fmaxf(sc[0][r], sc[1][r]), fmaxf(sc[2][r], sc[3][r]));
#pragma unroll
      for (int msk = 1; msk < 16; msk <<= 1) x = fmaxf(x, __shfl_xor(x, msk, 64));
      pm[r] = x;
    }
#pragma unroll
    for (int r = 0; r < 4; ++r) {
      float mn = fmaxf(m[r], pm[r]);
      scale[r] = __expf(m[r] - mn);
      m[r] = mn;
    }
    float ps[4] = {0.f, 0.f, 0.f, 0.f};
#pragma unroll
    for (int c = 0; c < 4; ++c)
#pragma unroll
      for (int r = 0; r < 4; ++r) {
        float p = __expf(sc[c][r] - m[r]);
        sc[c][r] = p;
        ps[r] += p;
      }
#pragma unroll
    for (int r = 0; r < 4; ++r) {
#pragma unroll
      for (int msk = 1; msk < 16; msk <<= 1) ps[r] += __shfl_xor(ps[r], msk, 64);
      l[r] = l[r] * scale[r] + ps[r];
    }
#pragma unroll
    for (int c = 0; c < 4; ++c)
#pragma unroll
      for (int r = 0; r < 4; ++r) o[c][r] *= scale[r];

#pragma unroll
    for (int c = 0; c < 4; ++c)
#pragma unroll
      for (int r = 0; r < 4; ++r)
        p_lds[w][g * 4 + r][c * 16 + li] = f2bf(sc[c][r]);

    // PV: A = P fragment (from p_lds), B = V^T fragment (vector read from vt).
#pragma unroll
    for (int ks = 0; ks < 2; ++ks) {
      bf8 pa = *(const bf8*)&p_lds[w][li][ks * 32 + g * 8];
#pragma unroll
      for (int c = 0; c < 4; ++c) {
        int d  = c * 16 + li;
        int kb = (ks * 32 + g * 8) ^ (((d >> 3) & 7) << 3);
        bf8 vb = *(const bf8*)&vt[d][kb];
        o[c] = __builtin_amdgcn_mfma_f32_16x16x32_bf16(pa, vb, o[c], 0, 0, 0);
      }
    }
  }

#pragma unroll
  for (int c = 0; c < 4; ++c)
#pragma unroll
    for (int r = 0; r < 4; ++r) {
      int row = q0 + w * 16 + g * 4 + r;
      Op[(size_t)row * D_ + c * 16 + li] = f2bf(o[c][r] / l[r]);
    }
}

extern "C" void kernel_launch(void* const* d_in, const int* in_sizes, int n_in,
                              void* d_out, int out_size, void* d_ws, size_t ws_size,
                              hipStream_t stream) {
  // Input remap guard: x is the only 6291456-elem input.
  const void *xv, *Wqv, *Wkv, *Wvv, *Wov, *tv;
  if (in_sizes[0] == M_ * D_) {
    xv = d_in[0]; Wqv = d_in[1]; Wkv = d_in[2]; Wvv = d_in[3]; Wov = d_in[4]; tv = d_in[5];
  } else {
    Wkv = d_in[0]; Wov = d_in[1]; Wqv = d_in[2]; Wvv = d_in[3]; tv = d_in[4]; xv = d_in[5];
  }
  const float* x    = (const float*)xv;
  const float* Wq   = (const float*)Wqv;
  const float* Wk   = (const float*)Wkv;
  const float* Wv   = (const float*)Wvv;
  const float* Wo   = (const float*)Wov;
  const float* temp = (const float*)tv;

  const size_t SZ  = (size_t)M_ * D_;   // 6291456
  const size_t WSZ = (size_t)D_ * D_;   // 589824
  u16* ws = (u16*)d_ws;
  u16* Qb = ws;
  u16* Kb = ws + SZ;
  u16* Vb = ws + 2 * SZ;
  u16* XB = (u16*)d_out;   // bf16(x) staged in d_out (scratch until final GEMM)

  const bool stageW = ws_size >= (3 * SZ + 4 * WSZ) * sizeof(u16);
  u16* Wqb = ws + 3 * SZ;
  u16* Wkb = Wqb + WSZ;
  u16* Wvb = Wkb + WSZ;
  u16* Wob = Wvb + WSZ;

  stage_cvt<<<2048, 256, 0, stream>>>(x, XB, (int)(SZ / 4));

  dim3 gg(M_ / 64, D_ / 128), bb(256);
  if (stageW) {
    stage_cvt<<<576, 256, 0, stream>>>(Wq, Wqb, (int)(WSZ / 4));
    stage_cvt<<<576, 256, 0, stream>>>(Wk, Wkb, (int)(WSZ / 4));
    stage_cvt<<<576, 256, 0, stream>>>(Wv, Wvb, (int)(WSZ / 4));
    stage_cvt<<<576, 256, 0, stream>>>(Wo, Wob, (int)(WSZ / 4));
    gemm_fused<1, 2><<<gg, bb, 0, stream>>>(XB, Wqb, Qb, nullptr, temp, M_, D_, D_);
    gemm_fused<1, 1><<<gg, bb, 0, stream>>>(XB, Wkb, Kb, nullptr, temp, M_, D_, D_);
    gemm_fused<1, 0><<<gg, bb, 0, stream>>>(XB, Wvb, Vb, nullptr, temp, M_, D_, D_);
  } else {
    gemm_fused<0, 2><<<gg, bb, 0, stream>>>(XB, Wq, Qb, nullptr, temp, M_, D_, D_);
    gemm_fused<0, 1><<<gg, bb, 0, stream>>>(XB, Wk, Kb, nullptr, temp, M_, D_, D_);
    gemm_fused<0, 0><<<gg, bb, 0, stream>>>(XB, Wv, Vb, nullptr, temp, M_, D_, D_);
  }

  // attention output overwrites Qb (safe: per-block exclusive rows)
  flash_attn<<<dim3(S_ / 64, B_ * H_), 256, 0, stream>>>(Qb, Kb, Vb, Qb);

  // final GEMM: f32 output
  if (stageW) gemm_fused<1, 3><<<gg, bb, 0, stream>>>(Qb, Wob, nullptr, (float*)d_out, temp, M_, D_, D_);
  else        gemm_fused<0, 3><<<gg, bb, 0, stream>>>(Qb, Wo,  nullptr, (float*)d_out, temp, M_, D_, D_);
}

// Round 11
// 386.484 us; speedup vs baseline: 169.5384x; 1.1649x over previous
//
#include <hip/hip_runtime.h>
#include <hip/hip_bf16.h>

#define B_ 4
#define S_ 2048
#define D_ 768
#define H_ 12
#define HD_ 64
#define M_ (B_*S_)   // 8192

typedef __attribute__((ext_vector_type(8))) short bf8;
typedef __attribute__((ext_vector_type(4))) float f4;
typedef unsigned short u16;
typedef unsigned int   u32;

__device__ __forceinline__ float bf2f(u16 u) {
  union { u32 i; float f; } c; c.i = ((u32)u) << 16; return c.f;
}
__device__ __forceinline__ u16 f2bf(float x) {
  union { float f; u32 i; } c; c.f = x;
  u32 r = (c.i + 0x7FFFu + ((c.i >> 16) & 1u)) >> 16;
  return (u16)r;
}

// f32 -> bf16 (rne), vectorized x4, grid-stride.
__global__ __launch_bounds__(256) void stage_cvt(const float* __restrict__ in,
                                                 u16* __restrict__ out, int n4)
{
  for (int i = blockIdx.x * blockDim.x + threadIdx.x; i < n4; i += gridDim.x * blockDim.x) {
    float4 v = ((const float4*)in)[i];
    ushort4 o;
    o.x = f2bf(v.x); o.y = f2bf(v.y); o.z = f2bf(v.z); o.w = f2bf(v.w);
    ((ushort4*)out)[i] = o;
  }
}

__device__ __forceinline__ bf8 ldcvt8(const float* __restrict__ p) {
  float4 a = *(const float4*)p;
  float4 b = *(const float4*)(p + 4);
  bf8 r;
  r[0] = f2bf(a.x); r[1] = f2bf(a.y); r[2] = f2bf(a.z); r[3] = f2bf(a.w);
  r[4] = f2bf(b.x); r[5] = f2bf(b.y); r[6] = f2bf(b.z); r[7] = f2bf(b.w);
  return r;
}

// C[m][n] = sum_k A[m][k] * W[n][k]; A bf16 [M,K]; W bf16 (WBF16=1) or f32.
// EPI: 0 = bf16 store; 1 = head-L2-normalize; 2 = normalize*temp[h]; 3 = f32 store.
template <int WBF16, int EPI>
__global__ __launch_bounds__(256) void gemm_fused(const u16* __restrict__ A,
                                                  const void* __restrict__ Wv,
                                                  u16* __restrict__ Cb,
                                                  float* __restrict__ Cf,
                                                  const float* __restrict__ temp,
                                                  int M, int N, int K)
{
  const int w  = threadIdx.x >> 6;
  const int ln = threadIdx.x & 63;
  const int li = ln & 15, g = ln >> 4;
  const int wr = w >> 1, wc = w & 1;
  const int row0 = blockIdx.x * 64 + wr * 32;
  const int col0 = blockIdx.y * 128 + wc * 64;

  const u16* Ap = A + (size_t)(row0 + li) * K + g * 8;

  f4 acc[2][4];
#pragma unroll
  for (int i = 0; i < 2; ++i)
#pragma unroll
    for (int j = 0; j < 4; ++j) acc[i][j] = (f4){0.f, 0.f, 0.f, 0.f};

  if (WBF16) {
    const u16* Wp = (const u16*)Wv + (size_t)(col0 + li) * K + g * 8;
    for (int k = 0; k < K; k += 32) {
      bf8 a0 = *(const bf8*)(Ap + k);
      bf8 a1 = *(const bf8*)(Ap + (size_t)16 * K + k);
      bf8 b0 = *(const bf8*)(Wp + k);
      bf8 b1 = *(const bf8*)(Wp + (size_t)16 * K + k);
      bf8 b2 = *(const bf8*)(Wp + (size_t)32 * K + k);
      bf8 b3 = *(const bf8*)(Wp + (size_t)48 * K + k);
      acc[0][0] = __builtin_amdgcn_mfma_f32_16x16x32_bf16(a0, b0, acc[0][0], 0, 0, 0);
      acc[0][1] = __builtin_amdgcn_mfma_f32_16x16x32_bf16(a0, b1, acc[0][1], 0, 0, 0);
      acc[0][2] = __builtin_amdgcn_mfma_f32_16x16x32_bf16(a0, b2, acc[0][2], 0, 0, 0);
      acc[0][3] = __builtin_amdgcn_mfma_f32_16x16x32_bf16(a0, b3, acc[0][3], 0, 0, 0);
      acc[1][0] = __builtin_amdgcn_mfma_f32_16x16x32_bf16(a1, b0, acc[1][0], 0, 0, 0);
      acc[1][1] = __builtin_amdgcn_mfma_f32_16x16x32_bf16(a1, b1, acc[1][1], 0, 0, 0);
      acc[1][2] = __builtin_amdgcn_mfma_f32_16x16x32_bf16(a1, b2, acc[1][2], 0, 0, 0);
      acc[1][3] = __builtin_amdgcn_mfma_f32_16x16x32_bf16(a1, b3, acc[1][3], 0, 0, 0);
    }
  } else {
    const float* Wp = (const float*)Wv + (size_t)(col0 + li) * K + g * 8;
    for (int k = 0; k < K; k += 32) {
      bf8 a0 = *(const bf8*)(Ap + k);
      bf8 a1 = *(const bf8*)(Ap + (size_t)16 * K + k);
      bf8 b0 = ldcvt8(Wp + k);
      bf8 b1 = ldcvt8(Wp + (size_t)16 * K + k);
      bf8 b2 = ldcvt8(Wp + (size_t)32 * K + k);
      bf8 b3 = ldcvt8(Wp + (size_t)48 * K + k);
      acc[0][0] = __builtin_amdgcn_mfma_f32_16x16x32_bf16(a0, b0, acc[0][0], 0, 0, 0);
      acc[0][1] = __builtin_amdgcn_mfma_f32_16x16x32_bf16(a0, b1, acc[0][1], 0, 0, 0);
      acc[0][2] = __builtin_amdgcn_mfma_f32_16x16x32_bf16(a0, b2, acc[0][2], 0, 0, 0);
      acc[0][3] = __builtin_amdgcn_mfma_f32_16x16x32_bf16(a0, b3, acc[0][3], 0, 0, 0);
      acc[1][0] = __builtin_amdgcn_mfma_f32_16x16x32_bf16(a1, b0, acc[1][0], 0, 0, 0);
      acc[1][1] = __builtin_amdgcn_mfma_f32_16x16x32_bf16(a1, b1, acc[1][1], 0, 0, 0);
      acc[1][2] = __builtin_amdgcn_mfma_f32_16x16x32_bf16(a1, b2, acc[1][2], 0, 0, 0);
      acc[1][3] = __builtin_amdgcn_mfma_f32_16x16x32_bf16(a1, b3, acc[1][3], 0, 0, 0);
    }
  }

  if (EPI == 1 || EPI == 2) {
    float tmul = 1.0f;
    if (EPI == 2) tmul = temp[(col0 >> 6)];
#pragma unroll
    for (int i = 0; i < 2; ++i)
#pragma unroll
      for (int r = 0; r < 4; ++r) {
        float ss = 0.f;
#pragma unroll
        for (int j = 0; j < 4; ++j) ss += acc[i][j][r] * acc[i][j][r];
#pragma unroll
        for (int msk = 1; msk < 16; msk <<= 1) ss += __shfl_xor(ss, msk, 64);
        float scl = tmul / fmaxf(sqrtf(ss), 1e-12f);
#pragma unroll
        for (int j = 0; j < 4; ++j) acc[i][j][r] *= scl;
      }
  }

#pragma unroll
  for (int i = 0; i < 2; ++i)
#pragma unroll
    for (int j = 0; j < 4; ++j)
#pragma unroll
      for (int r = 0; r < 4; ++r) {
        int row = row0 + i * 16 + g * 4 + r;
        int col = col0 + j * 16 + li;
        if (EPI == 3) Cf[(size_t)row * N + col] = acc[i][j][r];
        else          Cb[(size_t)row * N + col] = f2bf(acc[i][j][r]);
      }
}

// Flash attention v3: causal, temperature pre-folded into Q.
// 1D grid 1536 = 48 bh x 32 q-tiles, XCD-chunked (6 bh per XCD -> K/V L2-resident).
// 4 waves/block; wave owns 16 q-rows. V: ushort2 transposed staging + T14 async
// prefetch (raw barrier + lgkmcnt keeps next-tile loads in flight). P: XOR-swizzled
// LDS (conflict-free). O may alias Q (per-block exclusive rows, read-first).
__global__ __launch_bounds__(256) void flash_attn(const u16* __restrict__ Q,
                                                  const u16* __restrict__ K,
                                                  const u16* __restrict__ V,
                                                  u16* __restrict__ O)
{
  const int bid = blockIdx.x;
  const int vid = (bid & 7) * 192 + (bid >> 3);   // XCD-chunked remap
  const int bh  = vid >> 5;                        // 6 bh per XCD
  const int qt  = 31 - (vid & 31);                 // heavy tiles first
  const int b = bh / H_, h = bh % H_;
  const size_t base = (size_t)b * S_ * D_ + h * HD_;
  const u16* Qp = Q + base;
  const u16* Kp = K + base;
  const u16* Vp = V + base;
  u16*       Op = O + base;

  const int w  = threadIdx.x >> 6;
  const int ln = threadIdx.x & 63;
  const int li = ln & 15, g = ln >> 4;

  __shared__ __align__(16) u16 vt[64][72];         // V^T [d][key^(d&56)]
  __shared__ __align__(16) u16 p_lds[4][16][72];   // per-wave P, col^(g<<3) swizzle

  const int q0 = qt * 64;
  const int qrow = q0 + w * 16 + li;

  bf8 qf0 = *(const bf8*)(Qp + (size_t)qrow * D_ + g * 8);
  bf8 qf1 = *(const bf8*)(Qp + (size_t)qrow * D_ + 32 + g * 8);

  // V staging assignment: thread handles key pair (key2, key2+1) x d0..d0+7
  const int key2 = (threadIdx.x >> 3) * 2;
  const int d0   = (threadIdx.x & 7) * 8;
  const u16* vsrc = Vp + (size_t)key2 * D_ + d0;

  // prologue: prefetch V(tile 0)
  bf8 vc0 = *(const bf8*)(vsrc);
  bf8 vc1 = *(const bf8*)(vsrc + D_);

  f4 o[4];
  float m[4], l[4];
#pragma unroll
  for (int r = 0; r < 4; ++r) { m[r] = -__builtin_inff(); l[r] = 0.f; }
#pragma unroll
  for (int c = 0; c < 4; ++c) o[c] = (f4){0.f, 0.f, 0.f, 0.f};

  for (int kt = 0; kt <= qt; ++kt) {
    __syncthreads();   // (A) prior readers of vt done; drains vc0/vc1 loads (needed now)
    {
#pragma unroll
      for (int j = 0; j < 8; ++j) {
        ushort2 pr;
        pr.x = (u16)vc0[j]; pr.y = (u16)vc1[j];
        *(ushort2*)&vt[d0 + j][key2 ^ d0] = pr;
      }
    }
    if (kt < qt) {     // T14: issue next tile's V loads; in flight across compute
      const u16* s = vsrc + (size_t)(kt + 1) * 64 * D_;
      vc0 = *(const bf8*)(s);
      vc1 = *(const bf8*)(s + D_);
    }
    asm volatile("s_waitcnt lgkmcnt(0)" ::: "memory");  // LDS writes done (NOT vmcnt)
    __builtin_amdgcn_s_barrier();                        // (B) vt ready, loads stay in flight

    f4 sc[4];
#pragma unroll
    for (int c = 0; c < 4; ++c) sc[c] = (f4){0.f, 0.f, 0.f, 0.f};
#pragma unroll
    for (int c = 0; c < 4; ++c) {
      const u16* kb = Kp + (size_t)(kt * 64 + c * 16 + li) * D_ + g * 8;
      bf8 k0 = *(const bf8*)(kb);
      bf8 k1 = *(const bf8*)(kb + 32);
      sc[c] = __builtin_amdgcn_mfma_f32_16x16x32_bf16(qf0, k0, sc[c], 0, 0, 0);
      sc[c] = __builtin_amdgcn_mfma_f32_16x16x32_bf16(qf1, k1, sc[c], 0, 0, 0);
    }

    if (kt == qt) {
#pragma unroll
      for (int c = 0; c < 4; ++c)
#pragma unroll
        for (int r = 0; r < 4; ++r) {
          int col = kt * 64 + c * 16 + li;
          int row = q0 + w * 16 + g * 4 + r;
          if (col > row) sc[c][r] = -__builtin_inff();
        }
    }

    float pm[4], scale[4];
#pragma unroll
    for (int r = 0; r < 4; ++r) {
      float x = fmaxf(fmaxf(sc[0][r], sc[1][r]), fmaxf(sc[2][r], sc[3][r]));
#pragma unroll
      for (int msk = 1; msk < 16; msk <<= 1) x = fmaxf(x, __shfl_xor(x, msk, 64));
      pm[r] = x;
    }
#pragma unroll
    for (int r = 0; r < 4; ++r) {
      float mn = fmaxf(m[r], pm[r]);
      scale[r] = __expf(m[r] - mn);
      m[r] = mn;
    }
    float ps[4] = {0.f, 0.f, 0.f, 0.f};
#pragma unroll
    for (int c = 0; c < 4; ++c)
#pragma unroll
      for (int r = 0; r < 4; ++r) {
        float p = __expf(sc[c][r] - m[r]);
        sc[c][r] = p;
        ps[r] += p;
      }
#pragma unroll
    for (int r = 0; r < 4; ++r) {
#pragma unroll
      for (int msk = 1; msk < 16; msk <<= 1) ps[r] += __shfl_xor(ps[r], msk, 64);
      l[r] = l[r] * scale[r] + ps[r];
    }
#pragma unroll
    for (int c = 0; c < 4; ++c)
#pragma unroll
      for (int r = 0; r < 4; ++r) o[c][r] *= scale[r];

    // P -> LDS, XOR-swizzled: write col' = col ^ (g<<3)  (writer row = g*4+r)
#pragma unroll
    for (int c = 0; c < 4; ++c)
#pragma unroll
      for (int r = 0; r < 4; ++r)
        p_lds[w][g * 4 + r][(c * 16 + li) ^ (g << 3)] = f2bf(sc[c][r]);

    // PV: pa read col'' = col ^ ((li>>2)<<3); vb from vt with d-based swizzle
#pragma unroll
    for (int ks = 0; ks < 2; ++ks) {
      bf8 pa = *(const bf8*)&p_lds[w][li][(ks * 32 + g * 8) ^ ((li >> 2) << 3)];
#pragma unroll
      for (int c = 0; c < 4; ++c) {
        int d  = c * 16 + li;
        int kb = (ks * 32 + g * 8) ^ (d & 56);
        bf8 vb = *(const bf8*)&vt[d][kb];
        o[c] = __builtin_amdgcn_mfma_f32_16x16x32_bf16(pa, vb, o[c], 0, 0, 0);
      }
    }
  }

#pragma unroll
  for (int c = 0; c < 4; ++c)
#pragma unroll
    for (int r = 0; r < 4; ++r) {
      int row = q0 + w * 16 + g * 4 + r;
      Op[(size_t)row * D_ + c * 16 + li] = f2bf(o[c][r] / l[r]);
    }
}

extern "C" void kernel_launch(void* const* d_in, const int* in_sizes, int n_in,
                              void* d_out, int out_size, void* d_ws, size_t ws_size,
                              hipStream_t stream) {
  const void *xv, *Wqv, *Wkv, *Wvv, *Wov, *tv;
  if (in_sizes[0] == M_ * D_) {
    xv = d_in[0]; Wqv = d_in[1]; Wkv = d_in[2]; Wvv = d_in[3]; Wov = d_in[4]; tv = d_in[5];
  } else {
    Wkv = d_in[0]; Wov = d_in[1]; Wqv = d_in[2]; Wvv = d_in[3]; tv = d_in[4]; xv = d_in[5];
  }
  const float* x    = (const float*)xv;
  const float* Wq   = (const float*)Wqv;
  const float* Wk   = (const float*)Wkv;
  const float* Wv   = (const float*)Wvv;
  const float* Wo   = (const float*)Wov;
  const float* temp = (const float*)tv;

  const size_t SZ  = (size_t)M_ * D_;   // 6291456
  const size_t WSZ = (size_t)D_ * D_;   // 589824
  u16* ws = (u16*)d_ws;
  u16* Qb = ws;
  u16* Kb = ws + SZ;
  u16* Vb = ws + 2 * SZ;
  u16* XB = (u16*)d_out;   // bf16(x) staged in d_out (scratch until final GEMM)

  const bool stageW = ws_size >= (3 * SZ + 4 * WSZ) * sizeof(u16);
  u16* Wqb = ws + 3 * SZ;
  u16* Wkb = Wqb + WSZ;
  u16* Wvb = Wkb + WSZ;
  u16* Wob = Wvb + WSZ;

  stage_cvt<<<2048, 256, 0, stream>>>(x, XB, (int)(SZ / 4));

  dim3 gg(M_ / 64, D_ / 128), bb(256);
  if (stageW) {
    stage_cvt<<<576, 256, 0, stream>>>(Wq, Wqb, (int)(WSZ / 4));
    stage_cvt<<<576, 256, 0, stream>>>(Wk, Wkb, (int)(WSZ / 4));
    stage_cvt<<<576, 256, 0, stream>>>(Wv, Wvb, (int)(WSZ / 4));
    stage_cvt<<<576, 256, 0, stream>>>(Wo, Wob, (int)(WSZ / 4));
    gemm_fused<1, 2><<<gg, bb, 0, stream>>>(XB, Wqb, Qb, nullptr, temp, M_, D_, D_);
    gemm_fused<1, 1><<<gg, bb, 0, stream>>>(XB, Wkb, Kb, nullptr, temp, M_, D_, D_);
    gemm_fused<1, 0><<<gg, bb, 0, stream>>>(XB, Wvb, Vb, nullptr, temp, M_, D_, D_);
  } else {
    gemm_fused<0, 2><<<gg, bb, 0, stream>>>(XB, Wq, Qb, nullptr, temp, M_, D_, D_);
    gemm_fused<0, 1><<<gg, bb, 0, stream>>>(XB, Wk, Kb, nullptr, temp, M_, D_, D_);
    gemm_fused<0, 0><<<gg, bb, 0, stream>>>(XB, Wv, Vb, nullptr, temp, M_, D_, D_);
  }

  // attention output overwrites Qb (safe: per-block exclusive rows)
  flash_attn<<<1536, 256, 0, stream>>>(Qb, Kb, Vb, Qb);

  if (stageW) gemm_fused<1, 3><<<gg, bb, 0, stream>>>(Qb, Wob, nullptr, (float*)d_out, temp, M_, D_, D_);
  else        gemm_fused<0, 3><<<gg, bb, 0, stream>>>(Qb, Wo,  nullptr, (float*)d_out, temp, M_, D_, D_);
}

// Round 12
// 333.817 us; speedup vs baseline: 196.2864x; 1.1578x over previous
//
#include <hip/hip_runtime.h>
#include <hip/hip_bf16.h>

#define B_ 4
#define S_ 2048
#define D_ 768
#define H_ 12
#define HD_ 64
#define M_ (B_*S_)   // 8192

typedef __attribute__((ext_vector_type(8))) short bf8;
typedef __attribute__((ext_vector_type(4))) float f4;
typedef unsigned short u16;
typedef unsigned int   u32;

__device__ __forceinline__ float bf2f(u16 u) {
  union { u32 i; float f; } c; c.i = ((u32)u) << 16; return c.f;
}
__device__ __forceinline__ u16 f2bf(float x) {
  union { float f; u32 i; } c; c.f = x;
  u32 r = (c.i + 0x7FFFu + ((c.i >> 16) & 1u)) >> 16;
  return (u16)r;
}

// f32 -> bf16 (rne), vectorized x4, grid-stride.
__global__ __launch_bounds__(256) void stage_cvt(const float* __restrict__ in,
                                                 u16* __restrict__ out, int n4)
{
  for (int i = blockIdx.x * blockDim.x + threadIdx.x; i < n4; i += gridDim.x * blockDim.x) {
    float4 v = ((const float4*)in)[i];
    ushort4 o;
    o.x = f2bf(v.x); o.y = f2bf(v.y); o.z = f2bf(v.z); o.w = f2bf(v.w);
    ((ushort4*)out)[i] = o;
  }
}

__device__ __forceinline__ bf8 ldcvt8(const float* __restrict__ p) {
  float4 a = *(const float4*)p;
  float4 b = *(const float4*)(p + 4);
  bf8 r;
  r[0] = f2bf(a.x); r[1] = f2bf(a.y); r[2] = f2bf(a.z); r[3] = f2bf(a.w);
  r[4] = f2bf(b.x); r[5] = f2bf(b.y); r[6] = f2bf(b.z); r[7] = f2bf(b.w);
  return r;
}

// C[m][n] = sum_k A[m][k] * W[n][k]; A bf16 [M,K]; W bf16 (WBF16=1) or f32.
// EPI: 0 = bf16 store; 1 = head-L2-normalize; 2 = normalize*temp[h]; 3 = f32 store.
template <int WBF16, int EPI>
__global__ __launch_bounds__(256) void gemm_fused(const u16* __restrict__ A,
                                                  const void* __restrict__ Wv,
                                                  u16* __restrict__ Cb,
                                                  float* __restrict__ Cf,
                                                  const float* __restrict__ temp,
                                                  int M, int N, int K)
{
  const int w  = threadIdx.x >> 6;
  const int ln = threadIdx.x & 63;
  const int li = ln & 15, g = ln >> 4;
  const int wr = w >> 1, wc = w & 1;
  const int row0 = blockIdx.x * 64 + wr * 32;
  const int col0 = blockIdx.y * 128 + wc * 64;

  const u16* Ap = A + (size_t)(row0 + li) * K + g * 8;

  f4 acc[2][4];
#pragma unroll
  for (int i = 0; i < 2; ++i)
#pragma unroll
    for (int j = 0; j < 4; ++j) acc[i][j] = (f4){0.f, 0.f, 0.f, 0.f};

  if (WBF16) {
    const u16* Wp = (const u16*)Wv + (size_t)(col0 + li) * K + g * 8;
    for (int k = 0; k < K; k += 32) {
      bf8 a0 = *(const bf8*)(Ap + k);
      bf8 a1 = *(const bf8*)(Ap + (size_t)16 * K + k);
      bf8 b0 = *(const bf8*)(Wp + k);
      bf8 b1 = *(const bf8*)(Wp + (size_t)16 * K + k);
      bf8 b2 = *(const bf8*)(Wp + (size_t)32 * K + k);
      bf8 b3 = *(const bf8*)(Wp + (size_t)48 * K + k);
      acc[0][0] = __builtin_amdgcn_mfma_f32_16x16x32_bf16(a0, b0, acc[0][0], 0, 0, 0);
      acc[0][1] = __builtin_amdgcn_mfma_f32_16x16x32_bf16(a0, b1, acc[0][1], 0, 0, 0);
      acc[0][2] = __builtin_amdgcn_mfma_f32_16x16x32_bf16(a0, b2, acc[0][2], 0, 0, 0);
      acc[0][3] = __builtin_amdgcn_mfma_f32_16x16x32_bf16(a0, b3, acc[0][3], 0, 0, 0);
      acc[1][0] = __builtin_amdgcn_mfma_f32_16x16x32_bf16(a1, b0, acc[1][0], 0, 0, 0);
      acc[1][1] = __builtin_amdgcn_mfma_f32_16x16x32_bf16(a1, b1, acc[1][1], 0, 0, 0);
      acc[1][2] = __builtin_amdgcn_mfma_f32_16x16x32_bf16(a1, b2, acc[1][2], 0, 0, 0);
      acc[1][3] = __builtin_amdgcn_mfma_f32_16x16x32_bf16(a1, b3, acc[1][3], 0, 0, 0);
    }
  } else {
    const float* Wp = (const float*)Wv + (size_t)(col0 + li) * K + g * 8;
    for (int k = 0; k < K; k += 32) {
      bf8 a0 = *(const bf8*)(Ap + k);
      bf8 a1 = *(const bf8*)(Ap + (size_t)16 * K + k);
      bf8 b0 = ldcvt8(Wp + k);
      bf8 b1 = ldcvt8(Wp + (size_t)16 * K + k);
      bf8 b2 = ldcvt8(Wp + (size_t)32 * K + k);
      bf8 b3 = ldcvt8(Wp + (size_t)48 * K + k);
      acc[0][0] = __builtin_amdgcn_mfma_f32_16x16x32_bf16(a0, b0, acc[0][0], 0, 0, 0);
      acc[0][1] = __builtin_amdgcn_mfma_f32_16x16x32_bf16(a0, b1, acc[0][1], 0, 0, 0);
      acc[0][2] = __builtin_amdgcn_mfma_f32_16x16x32_bf16(a0, b2, acc[0][2], 0, 0, 0);
      acc[0][3] = __builtin_amdgcn_mfma_f32_16x16x32_bf16(a0, b3, acc[0][3], 0, 0, 0);
      acc[1][0] = __builtin_amdgcn_mfma_f32_16x16x32_bf16(a1, b0, acc[1][0], 0, 0, 0);
      acc[1][1] = __builtin_amdgcn_mfma_f32_16x16x32_bf16(a1, b1, acc[1][1], 0, 0, 0);
      acc[1][2] = __builtin_amdgcn_mfma_f32_16x16x32_bf16(a1, b2, acc[1][2], 0, 0, 0);
      acc[1][3] = __builtin_amdgcn_mfma_f32_16x16x32_bf16(a1, b3, acc[1][3], 0, 0, 0);
    }
  }

  if (EPI == 1 || EPI == 2) {
    float tmul = 1.0f;
    if (EPI == 2) tmul = temp[(col0 >> 6)];
#pragma unroll
    for (int i = 0; i < 2; ++i)
#pragma unroll
      for (int r = 0; r < 4; ++r) {
        float ss = 0.f;
#pragma unroll
        for (int j = 0; j < 4; ++j) ss += acc[i][j][r] * acc[i][j][r];
#pragma unroll
        for (int msk = 1; msk < 16; msk <<= 1) ss += __shfl_xor(ss, msk, 64);
        float scl = tmul / fmaxf(sqrtf(ss), 1e-12f);
#pragma unroll
        for (int j = 0; j < 4; ++j) acc[i][j][r] *= scl;
      }
  }

#pragma unroll
  for (int i = 0; i < 2; ++i)
#pragma unroll
    for (int j = 0; j < 4; ++j)
#pragma unroll
      for (int r = 0; r < 4; ++r) {
        int row = row0 + i * 16 + g * 4 + r;
        int col = col0 + j * 16 + li;
        if (EPI == 3) Cf[(size_t)row * N + col] = acc[i][j][r];
        else          Cb[(size_t)row * N + col] = f2bf(acc[i][j][r]);
      }
}

// Flash attention v4: causal, temperature pre-folded into Q.
// 1D grid 1536 = 48 bh x 32 q-tiles, XCD-chunked. 4 waves/block, wave owns 16 q-rows.
// K AND V staged in LDS (K row-major padded-72, V transposed+swizzled) with T14
// register prefetch: tile kt+1's global loads issued right after kt's LDS write,
// draining at the next __syncthreads (which needs vmcnt(0) anyway).
// O may alias Q (per-block exclusive rows, read-first).
__global__ __launch_bounds__(256, 4) void flash_attn(const u16* __restrict__ Q,
                                                     const u16* __restrict__ K,
                                                     const u16* __restrict__ V,
                                                     u16* __restrict__ O)
{
  const int bid = blockIdx.x;
  const int vid = (bid & 7) * 192 + (bid >> 3);   // XCD-chunked remap
  const int bh  = vid >> 5;                        // 6 bh per XCD
  const int qt  = 31 - (vid & 31);                 // heavy tiles first
  const int b = bh / H_, h = bh % H_;
  const size_t base = (size_t)b * S_ * D_ + h * HD_;
  const u16* Qp = Q + base;
  const u16* Kp = K + base;
  const u16* Vp = V + base;
  u16*       Op = O + base;

  const int w  = threadIdx.x >> 6;
  const int ln = threadIdx.x & 63;
  const int li = ln & 15, g = ln >> 4;

  __shared__ __align__(16) u16 k_lds[64][72];      // K row-major [key][d], pad 72
  __shared__ __align__(16) u16 vt[64][72];         // V^T [d][key^(d&56)]
  __shared__ __align__(16) u16 p_lds[4][16][72];   // per-wave P, col^(g<<3) swizzle

  const int q0 = qt * 64;
  const int qrow = q0 + w * 16 + li;

  bf8 qf0 = *(const bf8*)(Qp + (size_t)qrow * D_ + g * 8);
  bf8 qf1 = *(const bf8*)(Qp + (size_t)qrow * D_ + 32 + g * 8);

  // staging assignment: thread owns key pair (key2, key2+1) x d0..d0+7 for K and V
  const int key2 = (threadIdx.x >> 3) * 2;
  const int d0   = (threadIdx.x & 7) * 8;
  const u16* ksrc = Kp + (size_t)key2 * D_ + d0;
  const u16* vsrc = Vp + (size_t)key2 * D_ + d0;

  // prologue: prefetch K/V tile 0 into registers
  bf8 ka = *(const bf8*)(ksrc);
  bf8 kb = *(const bf8*)(ksrc + D_);
  bf8 va = *(const bf8*)(vsrc);
  bf8 vb_ = *(const bf8*)(vsrc + D_);

  f4 o[4];
  float m[4], l[4];
#pragma unroll
  for (int r = 0; r < 4; ++r) { m[r] = -__builtin_inff(); l[r] = 0.f; }
#pragma unroll
  for (int c = 0; c < 4; ++c) o[c] = (f4){0.f, 0.f, 0.f, 0.f};

  for (int kt = 0; kt <= qt; ++kt) {
    __syncthreads();   // prior LDS readers done; drains the in-flight K/V loads (needed now)
    {
      *(bf8*)&k_lds[key2][d0]     = ka;
      *(bf8*)&k_lds[key2 + 1][d0] = kb;
#pragma unroll
      for (int j = 0; j < 8; ++j) {
        ushort2 pr;
        pr.x = (u16)va[j]; pr.y = (u16)vb_[j];
        *(ushort2*)&vt[d0 + j][key2 ^ d0] = pr;
      }
    }
    if (kt < qt) {     // T14: issue next tile's loads; in flight across compute phase
      const u16* ks = ksrc + (size_t)(kt + 1) * 64 * D_;
      const u16* vs = vsrc + (size_t)(kt + 1) * 64 * D_;
      ka  = *(const bf8*)(ks);
      kb  = *(const bf8*)(ks + D_);
      va  = *(const bf8*)(vs);
      vb_ = *(const bf8*)(vs + D_);
    }
    asm volatile("s_waitcnt lgkmcnt(0)" ::: "memory");  // our LDS writes visible
    __builtin_amdgcn_s_barrier();                        // all writes visible; loads fly on

    // QK^T from LDS: fragment rows c*16+li, cols g*8 / 32+g*8 (2-way banks, free)
    f4 sc[4];
#pragma unroll
    for (int c = 0; c < 4; ++c) sc[c] = (f4){0.f, 0.f, 0.f, 0.f};
#pragma unroll
    for (int c = 0; c < 4; ++c) {
      bf8 k0 = *(const bf8*)&k_lds[c * 16 + li][g * 8];
      bf8 k1 = *(const bf8*)&k_lds[c * 16 + li][32 + g * 8];
      sc[c] = __builtin_amdgcn_mfma_f32_16x16x32_bf16(qf0, k0, sc[c], 0, 0, 0);
      sc[c] = __builtin_amdgcn_mfma_f32_16x16x32_bf16(qf1, k1, sc[c], 0, 0, 0);
    }

    if (kt == qt) {
#pragma unroll
      for (int c = 0; c < 4; ++c)
#pragma unroll
        for (int r = 0; r < 4; ++r) {
          int col = kt * 64 + c * 16 + li;
          int row = q0 + w * 16 + g * 4 + r;
          if (col > row) sc[c][r] = -__builtin_inff();
        }
    }

    float pm[4], scale[4];
#pragma unroll
    for (int r = 0; r < 4; ++r) {
      float x = fmaxf(fmaxf(sc[0][r], sc[1][r]), fmaxf(sc[2][r], sc[3][r]));
#pragma unroll
      for (int msk = 1; msk < 16; msk <<= 1) x = fmaxf(x, __shfl_xor(x, msk, 64));
      pm[r] = x;
    }
#pragma unroll
    for (int r = 0; r < 4; ++r) {
      float mn = fmaxf(m[r], pm[r]);
      scale[r] = __expf(m[r] - mn);
      m[r] = mn;
    }
    float ps[4] = {0.f, 0.f, 0.f, 0.f};
#pragma unroll
    for (int c = 0; c < 4; ++c)
#pragma unroll
      for (int r = 0; r < 4; ++r) {
        float p = __expf(sc[c][r] - m[r]);
        sc[c][r] = p;
        ps[r] += p;
      }
#pragma unroll
    for (int r = 0; r < 4; ++r) {
#pragma unroll
      for (int msk = 1; msk < 16; msk <<= 1) ps[r] += __shfl_xor(ps[r], msk, 64);
      l[r] = l[r] * scale[r] + ps[r];
    }
#pragma unroll
    for (int c = 0; c < 4; ++c)
#pragma unroll
      for (int r = 0; r < 4; ++r) o[c][r] *= scale[r];

    // P -> LDS, XOR-swizzled
#pragma unroll
    for (int c = 0; c < 4; ++c)
#pragma unroll
      for (int r = 0; r < 4; ++r)
        p_lds[w][g * 4 + r][(c * 16 + li) ^ (g << 3)] = f2bf(sc[c][r]);

    // PV
#pragma unroll
    for (int ks = 0; ks < 2; ++ks) {
      bf8 pa = *(const bf8*)&p_lds[w][li][(ks * 32 + g * 8) ^ ((li >> 2) << 3)];
#pragma unroll
      for (int c = 0; c < 4; ++c) {
        int d  = c * 16 + li;
        int kbx = (ks * 32 + g * 8) ^ (d & 56);
        bf8 vv = *(const bf8*)&vt[d][kbx];
        o[c] = __builtin_amdgcn_mfma_f32_16x16x32_bf16(pa, vv, o[c], 0, 0, 0);
      }
    }
  }

#pragma unroll
  for (int c = 0; c < 4; ++c)
#pragma unroll
    for (int r = 0; r < 4; ++r) {
      int row = q0 + w * 16 + g * 4 + r;
      Op[(size_t)row * D_ + c * 16 + li] = f2bf(o[c][r] / l[r]);
    }
}

extern "C" void kernel_launch(void* const* d_in, const int* in_sizes, int n_in,
                              void* d_out, int out_size, void* d_ws, size_t ws_size,
                              hipStream_t stream) {
  const void *xv, *Wqv, *Wkv, *Wvv, *Wov, *tv;
  if (in_sizes[0] == M_ * D_) {
    xv = d_in[0]; Wqv = d_in[1]; Wkv = d_in[2]; Wvv = d_in[3]; Wov = d_in[4]; tv = d_in[5];
  } else {
    Wkv = d_in[0]; Wov = d_in[1]; Wqv = d_in[2]; Wvv = d_in[3]; tv = d_in[4]; xv = d_in[5];
  }
  const float* x    = (const float*)xv;
  const float* Wq   = (const float*)Wqv;
  const float* Wk   = (const float*)Wkv;
  const float* Wv   = (const float*)Wvv;
  const float* Wo   = (const float*)Wov;
  const float* temp = (const float*)tv;

  const size_t SZ  = (size_t)M_ * D_;   // 6291456
  const size_t WSZ = (size_t)D_ * D_;   // 589824
  u16* ws = (u16*)d_ws;
  u16* Qb = ws;
  u16* Kb = ws + SZ;
  u16* Vb = ws + 2 * SZ;
  u16* XB = (u16*)d_out;   // bf16(x) staged in d_out (scratch until final GEMM)

  const bool stageW = ws_size >= (3 * SZ + 4 * WSZ) * sizeof(u16);
  u16* Wqb = ws + 3 * SZ;
  u16* Wkb = Wqb + WSZ;
  u16* Wvb = Wkb + WSZ;
  u16* Wob = Wvb + WSZ;

  stage_cvt<<<2048, 256, 0, stream>>>(x, XB, (int)(SZ / 4));

  dim3 gg(M_ / 64, D_ / 128), bb(256);
  if (stageW) {
    stage_cvt<<<576, 256, 0, stream>>>(Wq, Wqb, (int)(WSZ / 4));
    stage_cvt<<<576, 256, 0, stream>>>(Wk, Wkb, (int)(WSZ / 4));
    stage_cvt<<<576, 256, 0, stream>>>(Wv, Wvb, (int)(WSZ / 4));
    stage_cvt<<<576, 256, 0, stream>>>(Wo, Wob, (int)(WSZ / 4));
    gemm_fused<1, 2><<<gg, bb, 0, stream>>>(XB, Wqb, Qb, nullptr, temp, M_, D_, D_);
    gemm_fused<1, 1><<<gg, bb, 0, stream>>>(XB, Wkb, Kb, nullptr, temp, M_, D_, D_);
    gemm_fused<1, 0><<<gg, bb, 0, stream>>>(XB, Wvb, Vb, nullptr, temp, M_, D_, D_);
  } else {
    gemm_fused<0, 2><<<gg, bb, 0, stream>>>(XB, Wq, Qb, nullptr, temp, M_, D_, D_);
    gemm_fused<0, 1><<<gg, bb, 0, stream>>>(XB, Wk, Kb, nullptr, temp, M_, D_, D_);
    gemm_fused<0, 0><<<gg, bb, 0, stream>>>(XB, Wv, Vb, nullptr, temp, M_, D_, D_);
  }

  // attention output overwrites Qb (safe: per-block exclusive rows)
  flash_attn<<<1536, 256, 0, stream>>>(Qb, Kb, Vb, Qb);

  if (stageW) gemm_fused<1, 3><<<gg, bb, 0, stream>>>(Qb, Wob, nullptr, (float*)d_out, temp, M_, D_, D_);
  else        gemm_fused<0, 3><<<gg, bb, 0, stream>>>(Qb, Wo,  nullptr, (float*)d_out, temp, M_, D_, D_);
}

// Round 13
// 203.626 us; speedup vs baseline: 321.7853x; 1.6394x over previous
//
#include <hip/hip_runtime.h>
#include <hip/hip_bf16.h>

#define B_ 4
#define S_ 2048
#define D_ 768
#define H_ 12
#define HD_ 64
#define M_ (B_*S_)   // 8192

typedef __attribute__((ext_vector_type(8))) short bf8;
typedef __attribute__((ext_vector_type(4))) float f4;
typedef unsigned short u16;
typedef unsigned int   u32;

__device__ __forceinline__ float bf2f(u16 u) {
  union { u32 i; float f; } c; c.i = ((u32)u) << 16; return c.f;
}
__device__ __forceinline__ u16 f2bf(float x) {
  union { float f; u32 i; } c; c.f = x;
  u32 r = (c.i + 0x7FFFu + ((c.i >> 16) & 1u)) >> 16;
  return (u16)r;
}

// f32 -> bf16 (rne), vectorized x4, grid-stride.
__global__ __launch_bounds__(256) void stage_cvt(const float* __restrict__ in,
                                                 u16* __restrict__ out, int n4)
{
  for (int i = blockIdx.x * blockDim.x + threadIdx.x; i < n4; i += gridDim.x * blockDim.x) {
    float4 v = ((const float4*)in)[i];
    ushort4 o;
    o.x = f2bf(v.x); o.y = f2bf(v.y); o.z = f2bf(v.z); o.w = f2bf(v.w);
    ((ushort4*)out)[i] = o;
  }
}

__device__ __forceinline__ bf8 ldcvt8(const float* __restrict__ p) {
  float4 a = *(const float4*)p;
  float4 b = *(const float4*)(p + 4);
  bf8 r;
  r[0] = f2bf(a.x); r[1] = f2bf(a.y); r[2] = f2bf(a.z); r[3] = f2bf(a.w);
  r[4] = f2bf(b.x); r[5] = f2bf(b.y); r[6] = f2bf(b.z); r[7] = f2bf(b.w);
  return r;
}

#define MFMA_BF16 __builtin_amdgcn_mfma_f32_16x16x32_bf16

// GEMM v2: C[m][n] = sum_k A[m][k] * W[n][k]; A,W bf16; K = 768 fixed.
// Block 256 thr (2x2 waves), tile 64x128, BK=64, LDS-staged + T14 reg prefetch.
// EPI: 0 = bf16 store; 1 = head-L2-normalize; 2 = normalize*temp[h]; 3 = f32 store.
template <int EPI>
__global__ __launch_bounds__(256) void gemm_v2(const u16* __restrict__ A,
                                               const u16* __restrict__ W,
                                               u16* __restrict__ Cb,
                                               float* __restrict__ Cf,
                                               const float* __restrict__ temp)
{
  const int w  = threadIdx.x >> 6;
  const int ln = threadIdx.x & 63;
  const int li = ln & 15, g = ln >> 4;
  const int wr = w >> 1, wc = w & 1;
  const int row0 = blockIdx.x * 64;
  const int col0 = blockIdx.y * 128;

  __shared__ __align__(16) u16 a_lds[64][72];    // [m-row][k], stride 144B (2-way free reads)
  __shared__ __align__(16) u16 b_lds[128][72];   // [n-row][k]

  // staging: A 64x64 elems -> 2 bf8/thread; B 128x64 -> 4 bf8/thread
  const int rowA = threadIdx.x >> 2;             // 0..63
  const int cA   = (threadIdx.x & 3) * 8;        // chunks cA, cA+32
  const int rowB = threadIdx.x >> 1;             // 0..127
  const int cB   = (threadIdx.x & 1) * 32;       // chunks cB+{0,8,16,24}

  const u16* Asrc = A + (size_t)(row0 + rowA) * 768 + cA;
  const u16* Bsrc = W + (size_t)(col0 + rowB) * 768 + cB;

  // prologue: prefetch k-tile 0
  bf8 ra0 = *(const bf8*)(Asrc);
  bf8 ra1 = *(const bf8*)(Asrc + 32);
  bf8 rb0 = *(const bf8*)(Bsrc);
  bf8 rb1 = *(const bf8*)(Bsrc + 8);
  bf8 rb2 = *(const bf8*)(Bsrc + 16);
  bf8 rb3 = *(const bf8*)(Bsrc + 24);

  f4 acc[2][4];
#pragma unroll
  for (int i = 0; i < 2; ++i)
#pragma unroll
    for (int j = 0; j < 4; ++j) acc[i][j] = (f4){0.f, 0.f, 0.f, 0.f};

  for (int kt = 0; kt < 12; ++kt) {
    __syncthreads();   // prior readers done; in-flight loads drain (needed now)
    *(bf8*)&a_lds[rowA][cA]      = ra0;
    *(bf8*)&a_lds[rowA][cA + 32] = ra1;
    *(bf8*)&b_lds[rowB][cB]      = rb0;
    *(bf8*)&b_lds[rowB][cB + 8]  = rb1;
    *(bf8*)&b_lds[rowB][cB + 16] = rb2;
    *(bf8*)&b_lds[rowB][cB + 24] = rb3;
    if (kt < 11) {     // T14: next k-tile's loads fly across compute
      const u16* as = Asrc + (kt + 1) * 64;
      const u16* bs = Bsrc + (kt + 1) * 64;
      ra0 = *(const bf8*)(as);
      ra1 = *(const bf8*)(as + 32);
      rb0 = *(const bf8*)(bs);
      rb1 = *(const bf8*)(bs + 8);
      rb2 = *(const bf8*)(bs + 16);
      rb3 = *(const bf8*)(bs + 24);
    }
    asm volatile("s_waitcnt lgkmcnt(0)" ::: "memory");
    __builtin_amdgcn_s_barrier();

#pragma unroll
    for (int kk = 0; kk < 2; ++kk) {
      bf8 a0 = *(const bf8*)&a_lds[wr * 32 + li][kk * 32 + g * 8];
      bf8 a1 = *(const bf8*)&a_lds[wr * 32 + 16 + li][kk * 32 + g * 8];
      bf8 b0 = *(const bf8*)&b_lds[wc * 64 + li][kk * 32 + g * 8];
      bf8 b1 = *(const bf8*)&b_lds[wc * 64 + 16 + li][kk * 32 + g * 8];
      bf8 b2 = *(const bf8*)&b_lds[wc * 64 + 32 + li][kk * 32 + g * 8];
      bf8 b3 = *(const bf8*)&b_lds[wc * 64 + 48 + li][kk * 32 + g * 8];
      acc[0][0] = MFMA_BF16(a0, b0, acc[0][0], 0, 0, 0);
      acc[0][1] = MFMA_BF16(a0, b1, acc[0][1], 0, 0, 0);
      acc[0][2] = MFMA_BF16(a0, b2, acc[0][2], 0, 0, 0);
      acc[0][3] = MFMA_BF16(a0, b3, acc[0][3], 0, 0, 0);
      acc[1][0] = MFMA_BF16(a1, b0, acc[1][0], 0, 0, 0);
      acc[1][1] = MFMA_BF16(a1, b1, acc[1][1], 0, 0, 0);
      acc[1][2] = MFMA_BF16(a1, b2, acc[1][2], 0, 0, 0);
      acc[1][3] = MFMA_BF16(a1, b3, acc[1][3], 0, 0, 0);
    }
  }

  const int wrow0 = row0 + wr * 32;
  const int wcol0 = col0 + wc * 64;   // head-aligned (64-col head panel)

  if (EPI == 1 || EPI == 2) {
    float tmul = 1.0f;
    if (EPI == 2) tmul = temp[wcol0 >> 6];
#pragma unroll
    for (int i = 0; i < 2; ++i)
#pragma unroll
      for (int r = 0; r < 4; ++r) {
        float ss = 0.f;
#pragma unroll
        for (int j = 0; j < 4; ++j) ss += acc[i][j][r] * acc[i][j][r];
#pragma unroll
        for (int msk = 1; msk < 16; msk <<= 1) ss += __shfl_xor(ss, msk, 64);
        float scl = tmul / fmaxf(sqrtf(ss), 1e-12f);
#pragma unroll
        for (int j = 0; j < 4; ++j) acc[i][j][r] *= scl;
      }
  }

#pragma unroll
  for (int i = 0; i < 2; ++i)
#pragma unroll
    for (int j = 0; j < 4; ++j)
#pragma unroll
      for (int r = 0; r < 4; ++r) {
        int row = wrow0 + i * 16 + g * 4 + r;
        int col = wcol0 + j * 16 + li;
        if (EPI == 3) Cf[(size_t)row * 768 + col] = acc[i][j][r];
        else          Cb[(size_t)row * 768 + col] = f2bf(acc[i][j][r]);
      }
}

// Fallback GEMM (W f32 inline-cvt, direct-from-global) for !stageW.
template <int EPI>
__global__ __launch_bounds__(256) void gemm_wf32(const u16* __restrict__ A,
                                                 const float* __restrict__ W,
                                                 u16* __restrict__ Cb,
                                                 float* __restrict__ Cf,
                                                 const float* __restrict__ temp)
{
  const int w  = threadIdx.x >> 6;
  const int ln = threadIdx.x & 63;
  const int li = ln & 15, g = ln >> 4;
  const int wr = w >> 1, wc = w & 1;
  const int row0 = blockIdx.x * 64 + wr * 32;
  const int col0 = blockIdx.y * 128 + wc * 64;

  const u16*   Ap = A + (size_t)(row0 + li) * 768 + g * 8;
  const float* Wp = W + (size_t)(col0 + li) * 768 + g * 8;

  f4 acc[2][4];
#pragma unroll
  for (int i = 0; i < 2; ++i)
#pragma unroll
    for (int j = 0; j < 4; ++j) acc[i][j] = (f4){0.f, 0.f, 0.f, 0.f};

  for (int k = 0; k < 768; k += 32) {
    bf8 a0 = *(const bf8*)(Ap + k);
    bf8 a1 = *(const bf8*)(Ap + (size_t)16 * 768 + k);
    bf8 b0 = ldcvt8(Wp + k);
    bf8 b1 = ldcvt8(Wp + (size_t)16 * 768 + k);
    bf8 b2 = ldcvt8(Wp + (size_t)32 * 768 + k);
    bf8 b3 = ldcvt8(Wp + (size_t)48 * 768 + k);
    acc[0][0] = MFMA_BF16(a0, b0, acc[0][0], 0, 0, 0);
    acc[0][1] = MFMA_BF16(a0, b1, acc[0][1], 0, 0, 0);
    acc[0][2] = MFMA_BF16(a0, b2, acc[0][2], 0, 0, 0);
    acc[0][3] = MFMA_BF16(a0, b3, acc[0][3], 0, 0, 0);
    acc[1][0] = MFMA_BF16(a1, b0, acc[1][0], 0, 0, 0);
    acc[1][1] = MFMA_BF16(a1, b1, acc[1][1], 0, 0, 0);
    acc[1][2] = MFMA_BF16(a1, b2, acc[1][2], 0, 0, 0);
    acc[1][3] = MFMA_BF16(a1, b3, acc[1][3], 0, 0, 0);
  }

  if (EPI == 1 || EPI == 2) {
    float tmul = 1.0f;
    if (EPI == 2) tmul = temp[col0 >> 6];
#pragma unroll
    for (int i = 0; i < 2; ++i)
#pragma unroll
      for (int r = 0; r < 4; ++r) {
        float ss = 0.f;
#pragma unroll
        for (int j = 0; j < 4; ++j) ss += acc[i][j][r] * acc[i][j][r];
#pragma unroll
        for (int msk = 1; msk < 16; msk <<= 1) ss += __shfl_xor(ss, msk, 64);
        float scl = tmul / fmaxf(sqrtf(ss), 1e-12f);
#pragma unroll
        for (int j = 0; j < 4; ++j) acc[i][j][r] *= scl;
      }
  }

#pragma unroll
  for (int i = 0; i < 2; ++i)
#pragma unroll
    for (int j = 0; j < 4; ++j)
#pragma unroll
      for (int r = 0; r < 4; ++r) {
        int row = row0 + i * 16 + g * 4 + r;
        int col = col0 + j * 16 + li;
        if (EPI == 3) Cf[(size_t)row * 768 + col] = acc[i][j][r];
        else          Cb[(size_t)row * 768 + col] = f2bf(acc[i][j][r]);
      }
}

// Flash attention v4 (unchanged from R12): causal, temperature pre-folded into Q.
__global__ __launch_bounds__(256, 4) void flash_attn(const u16* __restrict__ Q,
                                                     const u16* __restrict__ K,
                                                     const u16* __restrict__ V,
                                                     u16* __restrict__ O)
{
  const int bid = blockIdx.x;
  const int vid = (bid & 7) * 192 + (bid >> 3);
  const int bh  = vid >> 5;
  const int qt  = 31 - (vid & 31);
  const int b = bh / H_, h = bh % H_;
  const size_t base = (size_t)b * S_ * D_ + h * HD_;
  const u16* Qp = Q + base;
  const u16* Kp = K + base;
  const u16* Vp = V + base;
  u16*       Op = O + base;

  const int w  = threadIdx.x >> 6;
  const int ln = threadIdx.x & 63;
  const int li = ln & 15, g = ln >> 4;

  __shared__ __align__(16) u16 k_lds[64][72];
  __shared__ __align__(16) u16 vt[64][72];
  __shared__ __align__(16) u16 p_lds[4][16][72];

  const int q0 = qt * 64;
  const int qrow = q0 + w * 16 + li;

  bf8 qf0 = *(const bf8*)(Qp + (size_t)qrow * D_ + g * 8);
  bf8 qf1 = *(const bf8*)(Qp + (size_t)qrow * D_ + 32 + g * 8);

  const int key2 = (threadIdx.x >> 3) * 2;
  const int d0   = (threadIdx.x & 7) * 8;
  const u16* ksrc = Kp + (size_t)key2 * D_ + d0;
  const u16* vsrc = Vp + (size_t)key2 * D_ + d0;

  bf8 ka = *(const bf8*)(ksrc);
  bf8 kb = *(const bf8*)(ksrc + D_);
  bf8 va = *(const bf8*)(vsrc);
  bf8 vb_ = *(const bf8*)(vsrc + D_);

  f4 o[4];
  float m[4], l[4];
#pragma unroll
  for (int r = 0; r < 4; ++r) { m[r] = -__builtin_inff(); l[r] = 0.f; }
#pragma unroll
  for (int c = 0; c < 4; ++c) o[c] = (f4){0.f, 0.f, 0.f, 0.f};

  for (int kt = 0; kt <= qt; ++kt) {
    __syncthreads();
    {
      *(bf8*)&k_lds[key2][d0]     = ka;
      *(bf8*)&k_lds[key2 + 1][d0] = kb;
#pragma unroll
      for (int j = 0; j < 8; ++j) {
        ushort2 pr;
        pr.x = (u16)va[j]; pr.y = (u16)vb_[j];
        *(ushort2*)&vt[d0 + j][key2 ^ d0] = pr;
      }
    }
    if (kt < qt) {
      const u16* ks = ksrc + (size_t)(kt + 1) * 64 * D_;
      const u16* vs = vsrc + (size_t)(kt + 1) * 64 * D_;
      ka  = *(const bf8*)(ks);
      kb  = *(const bf8*)(ks + D_);
      va  = *(const bf8*)(vs);
      vb_ = *(const bf8*)(vs + D_);
    }
    asm volatile("s_waitcnt lgkmcnt(0)" ::: "memory");
    __builtin_amdgcn_s_barrier();

    f4 sc[4];
#pragma unroll
    for (int c = 0; c < 4; ++c) sc[c] = (f4){0.f, 0.f, 0.f, 0.f};
#pragma unroll
    for (int c = 0; c < 4; ++c) {
      bf8 k0 = *(const bf8*)&k_lds[c * 16 + li][g * 8];
      bf8 k1 = *(const bf8*)&k_lds[c * 16 + li][32 + g * 8];
      sc[c] = MFMA_BF16(qf0, k0, sc[c], 0, 0, 0);
      sc[c] = MFMA_BF16(qf1, k1, sc[c], 0, 0, 0);
    }

    if (kt == qt) {
#pragma unroll
      for (int c = 0; c < 4; ++c)
#pragma unroll
        for (int r = 0; r < 4; ++r) {
          int col = kt * 64 + c * 16 + li;
          int row = q0 + w * 16 + g * 4 + r;
          if (col > row) sc[c][r] = -__builtin_inff();
        }
    }

    float pm[4], scale[4];
#pragma unroll
    for (int r = 0; r < 4; ++r) {
      float x = fmaxf(fmaxf(sc[0][r], sc[1][r]), fmaxf(sc[2][r], sc[3][r]));
#pragma unroll
      for (int msk = 1; msk < 16; msk <<= 1) x = fmaxf(x, __shfl_xor(x, msk, 64));
      pm[r] = x;
    }
#pragma unroll
    for (int r = 0; r < 4; ++r) {
      float mn = fmaxf(m[r], pm[r]);
      scale[r] = __expf(m[r] - mn);
      m[r] = mn;
    }
    float ps[4] = {0.f, 0.f, 0.f, 0.f};
#pragma unroll
    for (int c = 0; c < 4; ++c)
#pragma unroll
      for (int r = 0; r < 4; ++r) {
        float p = __expf(sc[c][r] - m[r]);
        sc[c][r] = p;
        ps[r] += p;
      }
#pragma unroll
    for (int r = 0; r < 4; ++r) {
#pragma unroll
      for (int msk = 1; msk < 16; msk <<= 1) ps[r] += __shfl_xor(ps[r], msk, 64);
      l[r] = l[r] * scale[r] + ps[r];
    }
#pragma unroll
    for (int c = 0; c < 4; ++c)
#pragma unroll
      for (int r = 0; r < 4; ++r) o[c][r] *= scale[r];

#pragma unroll
    for (int c = 0; c < 4; ++c)
#pragma unroll
      for (int r = 0; r < 4; ++r)
        p_lds[w][g * 4 + r][(c * 16 + li) ^ (g << 3)] = f2bf(sc[c][r]);

#pragma unroll
    for (int ks = 0; ks < 2; ++ks) {
      bf8 pa = *(const bf8*)&p_lds[w][li][(ks * 32 + g * 8) ^ ((li >> 2) << 3)];
#pragma unroll
      for (int c = 0; c < 4; ++c) {
        int d  = c * 16 + li;
        int kbx = (ks * 32 + g * 8) ^ (d & 56);
        bf8 vv = *(const bf8*)&vt[d][kbx];
        o[c] = MFMA_BF16(pa, vv, o[c], 0, 0, 0);
      }
    }
  }

#pragma unroll
  for (int c = 0; c < 4; ++c)
#pragma unroll
    for (int r = 0; r < 4; ++r) {
      int row = q0 + w * 16 + g * 4 + r;
      Op[(size_t)row * D_ + c * 16 + li] = f2bf(o[c][r] / l[r]);
    }
}

extern "C" void kernel_launch(void* const* d_in, const int* in_sizes, int n_in,
                              void* d_out, int out_size, void* d_ws, size_t ws_size,
                              hipStream_t stream) {
  const void *xv, *Wqv, *Wkv, *Wvv, *Wov, *tv;
  if (in_sizes[0] == M_ * D_) {
    xv = d_in[0]; Wqv = d_in[1]; Wkv = d_in[2]; Wvv = d_in[3]; Wov = d_in[4]; tv = d_in[5];
  } else {
    Wkv = d_in[0]; Wov = d_in[1]; Wqv = d_in[2]; Wvv = d_in[3]; tv = d_in[4]; xv = d_in[5];
  }
  const float* x    = (const float*)xv;
  const float* Wq   = (const float*)Wqv;
  const float* Wk   = (const float*)Wkv;
  const float* Wv   = (const float*)Wvv;
  const float* Wo   = (const float*)Wov;
  const float* temp = (const float*)tv;

  const size_t SZ  = (size_t)M_ * D_;   // 6291456
  const size_t WSZ = (size_t)D_ * D_;   // 589824
  u16* ws = (u16*)d_ws;
  u16* Qb = ws;
  u16* Kb = ws + SZ;
  u16* Vb = ws + 2 * SZ;
  u16* XB = (u16*)d_out;   // bf16(x) staged in d_out (scratch until final GEMM)

  const bool stageW = ws_size >= (3 * SZ + 4 * WSZ) * sizeof(u16);
  u16* Wqb = ws + 3 * SZ;
  u16* Wkb = Wqb + WSZ;
  u16* Wvb = Wkb + WSZ;
  u16* Wob = Wvb + WSZ;

  stage_cvt<<<2048, 256, 0, stream>>>(x, XB, (int)(SZ / 4));

  dim3 gg(M_ / 64, D_ / 128), bb(256);
  if (stageW) {
    stage_cvt<<<576, 256, 0, stream>>>(Wq, Wqb, (int)(WSZ / 4));
    stage_cvt<<<576, 256, 0, stream>>>(Wk, Wkb, (int)(WSZ / 4));
    stage_cvt<<<576, 256, 0, stream>>>(Wv, Wvb, (int)(WSZ / 4));
    stage_cvt<<<576, 256, 0, stream>>>(Wo, Wob, (int)(WSZ / 4));
    gemm_v2<2><<<gg, bb, 0, stream>>>(XB, Wqb, Qb, nullptr, temp);
    gemm_v2<1><<<gg, bb, 0, stream>>>(XB, Wkb, Kb, nullptr, temp);
    gemm_v2<0><<<gg, bb, 0, stream>>>(XB, Wvb, Vb, nullptr, temp);
  } else {
    gemm_wf32<2><<<gg, bb, 0, stream>>>(XB, Wq, Qb, nullptr, temp);
    gemm_wf32<1><<<gg, bb, 0, stream>>>(XB, Wk, Kb, nullptr, temp);
    gemm_wf32<0><<<gg, bb, 0, stream>>>(XB, Wv, Vb, nullptr, temp);
  }

  // attention output overwrites Qb (safe: per-block exclusive rows)
  flash_attn<<<1536, 256, 0, stream>>>(Qb, Kb, Vb, Qb);

  if (stageW) gemm_v2<3><<<gg, bb, 0, stream>>>(Qb, Wob, nullptr, (float*)d_out, temp);
  else        gemm_wf32<3><<<gg, bb, 0, stream>>>(Qb, Wo, nullptr, (float*)d_out, temp);
}

// Round 14
// 160.147 us; speedup vs baseline: 409.1482x; 1.2715x over previous
//
#include <hip/hip_runtime.h>
#include <hip/hip_bf16.h>

#define B_ 4
#define S_ 2048
#define D_ 768
#define H_ 12
#define HD_ 64
#define M_ (B_*S_)   // 8192

typedef __attribute__((ext_vector_type(8))) short bf8;
typedef __attribute__((ext_vector_type(4))) float f4;
typedef unsigned short u16;
typedef unsigned int   u32;

__device__ __forceinline__ float bf2f(u16 u) {
  union { u32 i; float f; } c; c.i = ((u32)u) << 16; return c.f;
}
__device__ __forceinline__ u16 f2bf(float x) {
  union { float f; u32 i; } c; c.f = x;
  u32 r = (c.i + 0x7FFFu + ((c.i >> 16) & 1u)) >> 16;
  return (u16)r;
}

// f32 -> bf16 (rne), vectorized x4, grid-stride.
__global__ __launch_bounds__(256) void stage_cvt(const float* __restrict__ in,
                                                 u16* __restrict__ out, int n4)
{
  for (int i = blockIdx.x * blockDim.x + threadIdx.x; i < n4; i += gridDim.x * blockDim.x) {
    float4 v = ((const float4*)in)[i];
    ushort4 o;
    o.x = f2bf(v.x); o.y = f2bf(v.y); o.z = f2bf(v.z); o.w = f2bf(v.w);
    ((ushort4*)out)[i] = o;
  }
}

__device__ __forceinline__ bf8 ldcvt8(const float* __restrict__ p) {
  float4 a = *(const float4*)p;
  float4 b = *(const float4*)(p + 4);
  bf8 r;
  r[0] = f2bf(a.x); r[1] = f2bf(a.y); r[2] = f2bf(a.z); r[3] = f2bf(a.w);
  r[4] = f2bf(b.x); r[5] = f2bf(b.y); r[6] = f2bf(b.z); r[7] = f2bf(b.w);
  return r;
}

#define MFMA_BF16 __builtin_amdgcn_mfma_f32_16x16x32_bf16

// GEMM v2 (unchanged from R13): LDS-staged + T14 reg prefetch, tile 64x128, BK=64.
// EPI: 0 = bf16 store; 1 = head-L2-normalize; 2 = normalize*temp[h]; 3 = f32 store.
template <int EPI>
__global__ __launch_bounds__(256) void gemm_v2(const u16* __restrict__ A,
                                               const u16* __restrict__ W,
                                               u16* __restrict__ Cb,
                                               float* __restrict__ Cf,
                                               const float* __restrict__ temp)
{
  const int w  = threadIdx.x >> 6;
  const int ln = threadIdx.x & 63;
  const int li = ln & 15, g = ln >> 4;
  const int wr = w >> 1, wc = w & 1;
  const int row0 = blockIdx.x * 64;
  const int col0 = blockIdx.y * 128;

  __shared__ __align__(16) u16 a_lds[64][72];
  __shared__ __align__(16) u16 b_lds[128][72];

  const int rowA = threadIdx.x >> 2;
  const int cA   = (threadIdx.x & 3) * 8;
  const int rowB = threadIdx.x >> 1;
  const int cB   = (threadIdx.x & 1) * 32;

  const u16* Asrc = A + (size_t)(row0 + rowA) * 768 + cA;
  const u16* Bsrc = W + (size_t)(col0 + rowB) * 768 + cB;

  bf8 ra0 = *(const bf8*)(Asrc);
  bf8 ra1 = *(const bf8*)(Asrc + 32);
  bf8 rb0 = *(const bf8*)(Bsrc);
  bf8 rb1 = *(const bf8*)(Bsrc + 8);
  bf8 rb2 = *(const bf8*)(Bsrc + 16);
  bf8 rb3 = *(const bf8*)(Bsrc + 24);

  f4 acc[2][4];
#pragma unroll
  for (int i = 0; i < 2; ++i)
#pragma unroll
    for (int j = 0; j < 4; ++j) acc[i][j] = (f4){0.f, 0.f, 0.f, 0.f};

  for (int kt = 0; kt < 12; ++kt) {
    __syncthreads();
    *(bf8*)&a_lds[rowA][cA]      = ra0;
    *(bf8*)&a_lds[rowA][cA + 32] = ra1;
    *(bf8*)&b_lds[rowB][cB]      = rb0;
    *(bf8*)&b_lds[rowB][cB + 8]  = rb1;
    *(bf8*)&b_lds[rowB][cB + 16] = rb2;
    *(bf8*)&b_lds[rowB][cB + 24] = rb3;
    if (kt < 11) {
      const u16* as = Asrc + (kt + 1) * 64;
      const u16* bs = Bsrc + (kt + 1) * 64;
      ra0 = *(const bf8*)(as);
      ra1 = *(const bf8*)(as + 32);
      rb0 = *(const bf8*)(bs);
      rb1 = *(const bf8*)(bs + 8);
      rb2 = *(const bf8*)(bs + 16);
      rb3 = *(const bf8*)(bs + 24);
    }
    asm volatile("s_waitcnt lgkmcnt(0)" ::: "memory");
    __builtin_amdgcn_s_barrier();

#pragma unroll
    for (int kk = 0; kk < 2; ++kk) {
      bf8 a0 = *(const bf8*)&a_lds[wr * 32 + li][kk * 32 + g * 8];
      bf8 a1 = *(const bf8*)&a_lds[wr * 32 + 16 + li][kk * 32 + g * 8];
      bf8 b0 = *(const bf8*)&b_lds[wc * 64 + li][kk * 32 + g * 8];
      bf8 b1 = *(const bf8*)&b_lds[wc * 64 + 16 + li][kk * 32 + g * 8];
      bf8 b2 = *(const bf8*)&b_lds[wc * 64 + 32 + li][kk * 32 + g * 8];
      bf8 b3 = *(const bf8*)&b_lds[wc * 64 + 48 + li][kk * 32 + g * 8];
      acc[0][0] = MFMA_BF16(a0, b0, acc[0][0], 0, 0, 0);
      acc[0][1] = MFMA_BF16(a0, b1, acc[0][1], 0, 0, 0);
      acc[0][2] = MFMA_BF16(a0, b2, acc[0][2], 0, 0, 0);
      acc[0][3] = MFMA_BF16(a0, b3, acc[0][3], 0, 0, 0);
      acc[1][0] = MFMA_BF16(a1, b0, acc[1][0], 0, 0, 0);
      acc[1][1] = MFMA_BF16(a1, b1, acc[1][1], 0, 0, 0);
      acc[1][2] = MFMA_BF16(a1, b2, acc[1][2], 0, 0, 0);
      acc[1][3] = MFMA_BF16(a1, b3, acc[1][3], 0, 0, 0);
    }
  }

  const int wrow0 = row0 + wr * 32;
  const int wcol0 = col0 + wc * 64;

  if (EPI == 1 || EPI == 2) {
    float tmul = 1.0f;
    if (EPI == 2) tmul = temp[wcol0 >> 6];
#pragma unroll
    for (int i = 0; i < 2; ++i)
#pragma unroll
      for (int r = 0; r < 4; ++r) {
        float ss = 0.f;
#pragma unroll
        for (int j = 0; j < 4; ++j) ss += acc[i][j][r] * acc[i][j][r];
#pragma unroll
        for (int msk = 1; msk < 16; msk <<= 1) ss += __shfl_xor(ss, msk, 64);
        float scl = tmul / fmaxf(sqrtf(ss), 1e-12f);
#pragma unroll
        for (int j = 0; j < 4; ++j) acc[i][j][r] *= scl;
      }
  }

#pragma unroll
  for (int i = 0; i < 2; ++i)
#pragma unroll
    for (int j = 0; j < 4; ++j)
#pragma unroll
      for (int r = 0; r < 4; ++r) {
        int row = wrow0 + i * 16 + g * 4 + r;
        int col = wcol0 + j * 16 + li;
        if (EPI == 3) Cf[(size_t)row * 768 + col] = acc[i][j][r];
        else          Cb[(size_t)row * 768 + col] = f2bf(acc[i][j][r]);
      }
}

// Fallback GEMM (W f32 inline-cvt, direct-from-global) for !stageW.
template <int EPI>
__global__ __launch_bounds__(256) void gemm_wf32(const u16* __restrict__ A,
                                                 const float* __restrict__ W,
                                                 u16* __restrict__ Cb,
                                                 float* __restrict__ Cf,
                                                 const float* __restrict__ temp)
{
  const int w  = threadIdx.x >> 6;
  const int ln = threadIdx.x & 63;
  const int li = ln & 15, g = ln >> 4;
  const int wr = w >> 1, wc = w & 1;
  const int row0 = blockIdx.x * 64 + wr * 32;
  const int col0 = blockIdx.y * 128 + wc * 64;

  const u16*   Ap = A + (size_t)(row0 + li) * 768 + g * 8;
  const float* Wp = W + (size_t)(col0 + li) * 768 + g * 8;

  f4 acc[2][4];
#pragma unroll
  for (int i = 0; i < 2; ++i)
#pragma unroll
    for (int j = 0; j < 4; ++j) acc[i][j] = (f4){0.f, 0.f, 0.f, 0.f};

  for (int k = 0; k < 768; k += 32) {
    bf8 a0 = *(const bf8*)(Ap + k);
    bf8 a1 = *(const bf8*)(Ap + (size_t)16 * 768 + k);
    bf8 b0 = ldcvt8(Wp + k);
    bf8 b1 = ldcvt8(Wp + (size_t)16 * 768 + k);
    bf8 b2 = ldcvt8(Wp + (size_t)32 * 768 + k);
    bf8 b3 = ldcvt8(Wp + (size_t)48 * 768 + k);
    acc[0][0] = MFMA_BF16(a0, b0, acc[0][0], 0, 0, 0);
    acc[0][1] = MFMA_BF16(a0, b1, acc[0][1], 0, 0, 0);
    acc[0][2] = MFMA_BF16(a0, b2, acc[0][2], 0, 0, 0);
    acc[0][3] = MFMA_BF16(a0, b3, acc[0][3], 0, 0, 0);
    acc[1][0] = MFMA_BF16(a1, b0, acc[1][0], 0, 0, 0);
    acc[1][1] = MFMA_BF16(a1, b1, acc[1][1], 0, 0, 0);
    acc[1][2] = MFMA_BF16(a1, b2, acc[1][2], 0, 0, 0);
    acc[1][3] = MFMA_BF16(a1, b3, acc[1][3], 0, 0, 0);
  }

  if (EPI == 1 || EPI == 2) {
    float tmul = 1.0f;
    if (EPI == 2) tmul = temp[col0 >> 6];
#pragma unroll
    for (int i = 0; i < 2; ++i)
#pragma unroll
      for (int r = 0; r < 4; ++r) {
        float ss = 0.f;
#pragma unroll
        for (int j = 0; j < 4; ++j) ss += acc[i][j][r] * acc[i][j][r];
#pragma unroll
        for (int msk = 1; msk < 16; msk <<= 1) ss += __shfl_xor(ss, msk, 64);
        float scl = tmul / fmaxf(sqrtf(ss), 1e-12f);
#pragma unroll
        for (int j = 0; j < 4; ++j) acc[i][j][r] *= scl;
      }
  }

#pragma unroll
  for (int i = 0; i < 2; ++i)
#pragma unroll
    for (int j = 0; j < 4; ++j)
#pragma unroll
      for (int r = 0; r < 4; ++r) {
        int row = row0 + i * 16 + g * 4 + r;
        int col = col0 + j * 16 + li;
        if (EPI == 3) Cf[(size_t)row * 768 + col] = acc[i][j][r];
        else          Cb[(size_t)row * 768 + col] = f2bf(acc[i][j][r]);
      }
}

// Flash attention v5: FIXED-SHIFT softmax (exact for cosine-sim attention).
// Scores = temp[h] * (q_hat . k_hat), |score| <= C = |temp[h]|. Softmax is exactly
// shift-invariant, so p = exp(s - C) with NO running max, NO rescaling; row-sum
// deferred to epilogue (in-lane partials). Diagonal gives s = temp = C -> p = 1.
__global__ __launch_bounds__(256, 4) void flash_attn(const u16* __restrict__ Q,
                                                     const u16* __restrict__ K,
                                                     const u16* __restrict__ V,
                                                     u16* __restrict__ O,
                                                     const float* __restrict__ temp)
{
  const int bid = blockIdx.x;
  const int vid = (bid & 7) * 192 + (bid >> 3);
  const int bh  = vid >> 5;
  const int qt  = 31 - (vid & 31);
  const int b = bh / H_, h = bh % H_;
  const size_t base = (size_t)b * S_ * D_ + h * HD_;
  const u16* Qp = Q + base;
  const u16* Kp = K + base;
  const u16* Vp = V + base;
  u16*       Op = O + base;

  const float C = fabsf(temp[h]);

  const int w  = threadIdx.x >> 6;
  const int ln = threadIdx.x & 63;
  const int li = ln & 15, g = ln >> 4;

  __shared__ __align__(16) u16 k_lds[64][72];
  __shared__ __align__(16) u16 vt[64][72];
  __shared__ __align__(16) u16 p_lds[4][16][72];

  const int q0 = qt * 64;
  const int qrow = q0 + w * 16 + li;

  bf8 qf0 = *(const bf8*)(Qp + (size_t)qrow * D_ + g * 8);
  bf8 qf1 = *(const bf8*)(Qp + (size_t)qrow * D_ + 32 + g * 8);

  const int key2 = (threadIdx.x >> 3) * 2;
  const int d0   = (threadIdx.x & 7) * 8;
  const u16* ksrc = Kp + (size_t)key2 * D_ + d0;
  const u16* vsrc = Vp + (size_t)key2 * D_ + d0;

  bf8 ka = *(const bf8*)(ksrc);
  bf8 kb = *(const bf8*)(ksrc + D_);
  bf8 va = *(const bf8*)(vsrc);
  bf8 vb_ = *(const bf8*)(vsrc + D_);

  f4 o[4];
  float lp[4] = {0.f, 0.f, 0.f, 0.f};   // in-lane partial softmax denominators
#pragma unroll
  for (int c = 0; c < 4; ++c) o[c] = (f4){0.f, 0.f, 0.f, 0.f};

  for (int kt = 0; kt <= qt; ++kt) {
    __syncthreads();
    {
      *(bf8*)&k_lds[key2][d0]     = ka;
      *(bf8*)&k_lds[key2 + 1][d0] = kb;
#pragma unroll
      for (int j = 0; j < 8; ++j) {
        ushort2 pr;
        pr.x = (u16)va[j]; pr.y = (u16)vb_[j];
        *(ushort2*)&vt[d0 + j][key2 ^ d0] = pr;
      }
    }
    if (kt < qt) {
      const u16* ks = ksrc + (size_t)(kt + 1) * 64 * D_;
      const u16* vs = vsrc + (size_t)(kt + 1) * 64 * D_;
      ka  = *(const bf8*)(ks);
      kb  = *(const bf8*)(ks + D_);
      va  = *(const bf8*)(vs);
      vb_ = *(const bf8*)(vs + D_);
    }
    asm volatile("s_waitcnt lgkmcnt(0)" ::: "memory");
    __builtin_amdgcn_s_barrier();

    f4 sc[4];
#pragma unroll
    for (int c = 0; c < 4; ++c) sc[c] = (f4){0.f, 0.f, 0.f, 0.f};
#pragma unroll
    for (int c = 0; c < 4; ++c) {
      bf8 k0 = *(const bf8*)&k_lds[c * 16 + li][g * 8];
      bf8 k1 = *(const bf8*)&k_lds[c * 16 + li][32 + g * 8];
      sc[c] = MFMA_BF16(qf0, k0, sc[c], 0, 0, 0);
      sc[c] = MFMA_BF16(qf1, k1, sc[c], 0, 0, 0);
    }

    if (kt == qt) {
#pragma unroll
      for (int c = 0; c < 4; ++c)
#pragma unroll
        for (int r = 0; r < 4; ++r) {
          int col = kt * 64 + c * 16 + li;
          int row = q0 + w * 16 + g * 4 + r;
          if (col > row) sc[c][r] = -__builtin_inff();
        }
    }

    // fixed-shift softmax: p = exp(s - C); accumulate in-lane partial row sums
#pragma unroll
    for (int c = 0; c < 4; ++c)
#pragma unroll
      for (int r = 0; r < 4; ++r) {
        float p = __expf(sc[c][r] - C);
        sc[c][r] = p;
        lp[r] += p;
      }

    // P -> LDS, XOR-swizzled
#pragma unroll
    for (int c = 0; c < 4; ++c)
#pragma unroll
      for (int r = 0; r < 4; ++r)
        p_lds[w][g * 4 + r][(c * 16 + li) ^ (g << 3)] = f2bf(sc[c][r]);

    // PV
#pragma unroll
    for (int ks = 0; ks < 2; ++ks) {
      bf8 pa = *(const bf8*)&p_lds[w][li][(ks * 32 + g * 8) ^ ((li >> 2) << 3)];
#pragma unroll
      for (int c = 0; c < 4; ++c) {
        int d  = c * 16 + li;
        int kbx = (ks * 32 + g * 8) ^ (d & 56);
        bf8 vv = *(const bf8*)&vt[d][kbx];
        o[c] = MFMA_BF16(pa, vv, o[c], 0, 0, 0);
      }
    }
  }

  // epilogue: finish row sums (one shfl reduce), divide, store
  float l[4];
#pragma unroll
  for (int r = 0; r < 4; ++r) {
    float s = lp[r];
#pragma unroll
    for (int msk = 1; msk < 16; msk <<= 1) s += __shfl_xor(s, msk, 64);
    l[r] = s;
  }
#pragma unroll
  for (int c = 0; c < 4; ++c)
#pragma unroll
    for (int r = 0; r < 4; ++r) {
      int row = q0 + w * 16 + g * 4 + r;
      Op[(size_t)row * D_ + c * 16 + li] = f2bf(o[c][r] / l[r]);
    }
}

extern "C" void kernel_launch(void* const* d_in, const int* in_sizes, int n_in,
                              void* d_out, int out_size, void* d_ws, size_t ws_size,
                              hipStream_t stream) {
  const void *xv, *Wqv, *Wkv, *Wvv, *Wov, *tv;
  if (in_sizes[0] == M_ * D_) {
    xv = d_in[0]; Wqv = d_in[1]; Wkv = d_in[2]; Wvv = d_in[3]; Wov = d_in[4]; tv = d_in[5];
  } else {
    Wkv = d_in[0]; Wov = d_in[1]; Wqv = d_in[2]; Wvv = d_in[3]; tv = d_in[4]; xv = d_in[5];
  }
  const float* x    = (const float*)xv;
  const float* Wq   = (const float*)Wqv;
  const float* Wk   = (const float*)Wkv;
  const float* Wv   = (const float*)Wvv;
  const float* Wo   = (const float*)Wov;
  const float* temp = (const float*)tv;

  const size_t SZ  = (size_t)M_ * D_;   // 6291456
  const size_t WSZ = (size_t)D_ * D_;   // 589824
  u16* ws = (u16*)d_ws;
  u16* Qb = ws;
  u16* Kb = ws + SZ;
  u16* Vb = ws + 2 * SZ;
  u16* XB = (u16*)d_out;   // bf16(x) staged in d_out (scratch until final GEMM)

  const bool stageW = ws_size >= (3 * SZ + 4 * WSZ) * sizeof(u16);
  u16* Wqb = ws + 3 * SZ;
  u16* Wkb = Wqb + WSZ;
  u16* Wvb = Wkb + WSZ;
  u16* Wob = Wvb + WSZ;

  stage_cvt<<<2048, 256, 0, stream>>>(x, XB, (int)(SZ / 4));

  dim3 gg(M_ / 64, D_ / 128), bb(256);
  if (stageW) {
    stage_cvt<<<576, 256, 0, stream>>>(Wq, Wqb, (int)(WSZ / 4));
    stage_cvt<<<576, 256, 0, stream>>>(Wk, Wkb, (int)(WSZ / 4));
    stage_cvt<<<576, 256, 0, stream>>>(Wv, Wvb, (int)(WSZ / 4));
    stage_cvt<<<576, 256, 0, stream>>>(Wo, Wob, (int)(WSZ / 4));
    gemm_v2<2><<<gg, bb, 0, stream>>>(XB, Wqb, Qb, nullptr, temp);
    gemm_v2<1><<<gg, bb, 0, stream>>>(XB, Wkb, Kb, nullptr, temp);
    gemm_v2<0><<<gg, bb, 0, stream>>>(XB, Wvb, Vb, nullptr, temp);
  } else {
    gemm_wf32<2><<<gg, bb, 0, stream>>>(XB, Wq, Qb, nullptr, temp);
    gemm_wf32<1><<<gg, bb, 0, stream>>>(XB, Wk, Kb, nullptr, temp);
    gemm_wf32<0><<<gg, bb, 0, stream>>>(XB, Wv, Vb, nullptr, temp);
  }

  // attention output overwrites Qb (safe: per-block exclusive rows)
  flash_attn<<<1536, 256, 0, stream>>>(Qb, Kb, Vb, Qb, temp);

  if (stageW) gemm_v2<3><<<gg, bb, 0, stream>>>(Qb, Wob, nullptr, (float*)d_out, temp);
  else        gemm_wf32<3><<<gg, bb, 0, stream>>>(Qb, Wo, nullptr, (float*)d_out, temp);
}